// Round 1
// baseline (440.601 us; speedup 1.0000x reference)
//
#include <hip/hip_runtime.h>

typedef __bf16 bf16;
typedef float f32x4 __attribute__((ext_vector_type(4)));
typedef bf16 bf16x8 __attribute__((ext_vector_type(8)));
typedef bf16 bf16x4 __attribute__((ext_vector_type(4)));
typedef unsigned int uint;

// Problem constants: B=2 S=4096 D=768 H=12 HD=64 BLK=32 NBR=128 MB=24 NUM_BLOCK=1024 DIAG_N=3

__device__ __forceinline__ void llds16(const bf16* g, bf16* l) {
    __builtin_amdgcn_global_load_lds((const __attribute__((address_space(1))) uint*)g,
                                     (__attribute__((address_space(3))) uint*)l, 16, 0, 0);
}

__device__ __forceinline__ uint sortable(float f) {
    uint u = __float_as_uint(f);
    return u ^ (uint)(((int)u >> 31) | 0x80000000);
}

// ---------------- prep: conversions / block sums ----------------
__global__ void k_convX(const float* __restrict__ X, bf16* __restrict__ Xb) {
    int i = blockIdx.x * 256 + threadIdx.x;          // over 8192*768/4
    if (i >= 1572864) return;
    float4 f = ((const float4*)X)[i];
    bf16x4 o = {(bf16)f.x, (bf16)f.y, (bf16)f.z, (bf16)f.w};
    ((bf16x4*)Xb)[i] = o;
}

__global__ void k_convW(const float* __restrict__ Wq, const float* __restrict__ Wk,
                        const float* __restrict__ Wv, bf16* __restrict__ Wb) {
    int i = blockIdx.x * 256 + threadIdx.x;          // over 2304*768/4
    if (i >= 442368) return;
    int n = (i << 2) / 768;
    int k = (i << 2) % 768;
    const float* W = n < 768 ? Wq : (n < 1536 ? Wk : Wv);
    int nn = n - (n < 768 ? 0 : (n < 1536 ? 768 : 1536));
    float4 f = *(const float4*)(W + (size_t)nn * 768 + k);
    bf16x4 o = {(bf16)f.x, (bf16)f.y, (bf16)f.z, (bf16)f.w};
    ((bf16x4*)Wb)[i] = o;
}

__global__ void k_xhsum(const float* __restrict__ X, const float* __restrict__ mask,
                        float* __restrict__ Xh) {
    int gid = blockIdx.x * 256 + threadIdx.x;        // over 256*192 (rows x float4-cols)
    if (gid >= 256 * 192) return;
    int c4 = gid % 192, row = gid / 192;             // row = b*128 + nbr
    int b = row >> 7, nbr = row & 127;
    const float4* xp = (const float4*)(X + ((size_t)(b * 4096 + nbr * 32)) * 768) + c4;
    const float* mp = mask + b * 4096 + nbr * 32;
    float4 s = {0.f, 0.f, 0.f, 0.f};
    for (int t = 0; t < 32; ++t) {
        float4 v = xp[(size_t)t * 192];
        float m = mp[t];
        s.x += v.x * m; s.y += v.y * m; s.z += v.z * m; s.w += v.w * m;
    }
    *((float4*)(Xh + (size_t)row * 768) + c4) = s;
}

__global__ void k_tc(const float* __restrict__ mask, float* __restrict__ tc) {
    int i = threadIdx.x;                              // 256 = B*NBR
    int b = i >> 7, nbr = i & 127;
    float s = 0.f;
    for (int t = 0; t < 32; ++t) s += mask[b * 4096 + nbr * 32 + t];
    tc[i] = s;
}

// ---------------- QKV projection GEMM (bf16 MFMA, m97 structure) ----------------
// Y[8192 x 2304] = Xb[8192x768] @ Wb[2304x768]^T + bias, epilogue scatters into
// Q/K [mb][s][d] bf16 and V transposed [mb][nb][d][t] bf16 (for PV B-fragments).
__global__ __launch_bounds__(256)
void k_gemm_qkv(const bf16* __restrict__ Xb, const bf16* __restrict__ Wb,
                const float* __restrict__ bq, const float* __restrict__ bk,
                const float* __restrict__ bv, const float* __restrict__ mask,
                bf16* __restrict__ Qb, bf16* __restrict__ Kb, bf16* __restrict__ Vt) {
    __shared__ bf16 As[128 * 32];
    __shared__ bf16 Bs[128 * 32];
    const int tid = threadIdx.x;
    const int wave = tid >> 6, lane = tid & 63;
    const int quad = lane >> 4, l16 = lane & 15;
    const int wr = wave >> 1, wc = wave & 1;
    const int m0 = blockIdx.x * 128, n0 = blockIdx.y * 128;
    const int sr = lane >> 2, sc = (lane & 3) * 8;

    f32x4 acc[4][4] = {};

    for (int k0 = 0; k0 < 768; k0 += 32) {
        __syncthreads();
#pragma unroll
        for (int it = 0; it < 2; ++it) {
            int rbase = wave * 32 + it * 16;
            llds16(Xb + (size_t)(m0 + rbase + sr) * 768 + k0 + sc, &As[rbase * 32]);
            llds16(Wb + (size_t)(n0 + rbase + sr) * 768 + k0 + sc, &Bs[rbase * 32]);
        }
        __syncthreads();
        bf16x8 a[4], b[4];
#pragma unroll
        for (int i = 0; i < 4; ++i)
            a[i] = *(const bf16x8*)&As[(wr * 64 + i * 16 + l16) * 32 + quad * 8];
#pragma unroll
        for (int i = 0; i < 4; ++i)
            b[i] = *(const bf16x8*)&Bs[(wc * 64 + i * 16 + l16) * 32 + quad * 8];
#pragma unroll
        for (int i = 0; i < 4; ++i)
#pragma unroll
            for (int j = 0; j < 4; ++j)
                acc[i][j] = __builtin_amdgcn_mfma_f32_16x16x32_bf16(a[i], b[j], acc[i][j], 0, 0, 0);
    }

    const int which = n0 / 768;                       // uniform per block
    const float* bias = which == 0 ? bq : (which == 1 ? bk : bv);
#pragma unroll
    for (int i = 0; i < 4; ++i) {
        int mrow = m0 + wr * 64 + i * 16 + quad * 4;
#pragma unroll
        for (int j = 0; j < 4; ++j) {
            int n = n0 + wc * 64 + j * 16 + l16;
            int hcol = n - which * 768;
            int h = hcol >> 6, d = hcol & 63;
#pragma unroll
            for (int r = 0; r < 4; ++r) {
                int mm = mrow + r;
                int bidx = mm >> 12, s = mm & 4095;
                float y = (acc[i][j][r] + bias[hcol]) * mask[(bidx << 12) + s];
                bf16 v = (bf16)y;
                size_t mb = (size_t)(bidx * 12 + h);
                if (which == 0)      Qb[((mb << 12) + s) * 64 + d] = v;
                else if (which == 1) Kb[((mb << 12) + s) * 64 + d] = v;
                else                 Vt[((mb * 128 + (s >> 5)) * 64 + d) * 32 + (s & 31)] = v;
            }
        }
    }
}

// ---------------- exact f32 low-res projections: Qh/Kh/Vh ----------------
// Qh[mb][nb][d] = (Xh_sum[b][nb] @ W^T + tc*b) / (tc + 1e-6)
__global__ __launch_bounds__(256)
void k_lowres(const float* __restrict__ Xh, const float* __restrict__ tc,
              const float* __restrict__ Wq, const float* __restrict__ Wk,
              const float* __restrict__ Wv, const float* __restrict__ bq,
              const float* __restrict__ bk, const float* __restrict__ bv,
              float* __restrict__ Qh, float* __restrict__ Kh, float* __restrict__ Vh) {
    int nb9 = blockIdx.x, rc = blockIdx.y, t = threadIdx.x;   // grid (9, 32)
    __shared__ float xsh[8 * 768];
    for (int idx = t; idx < 8 * 768; idx += 256)
        xsh[idx] = Xh[(size_t)(rc * 8) * 768 + idx];
    __syncthreads();
    int which = nb9 / 3;
    int wcol = (nb9 % 3) * 256 + t;
    const float* W = (which == 0 ? Wq : (which == 1 ? Wk : Wv)) + (size_t)wcol * 768;
    const float* bias = which == 0 ? bq : (which == 1 ? bk : bv);
    float acc[8] = {};
    for (int k = 0; k < 768; k += 4) {
        float4 w4 = *(const float4*)(W + k);
#pragma unroll
        for (int j = 0; j < 8; ++j) {
            float4 x4 = *(const float4*)&xsh[j * 768 + k];
            acc[j] += w4.x * x4.x + w4.y * x4.y + w4.z * x4.z + w4.w * x4.w;
        }
    }
    int h = wcol >> 6, d = wcol & 63;
    float bval = bias[wcol];
    float* dst = which == 0 ? Qh : (which == 1 ? Kh : Vh);
#pragma unroll
    for (int j = 0; j < 8; ++j) {
        int row = rc * 8 + j;
        int b = row >> 7, nbr = row & 127;
        float tcv = tc[row];
        float val = (acc[j] + tcv * bval) / (tcv + 1e-6f);
        dst[(((size_t)(b * 12 + h)) * 128 + nbr) * 64 + d] = val;
    }
}

// ---------------- low-res logits + row max (f32 exact) ----------------
__global__ __launch_bounds__(256)
void k_lowlogit(const float* __restrict__ Qh, const float* __restrict__ Kh,
                float* __restrict__ prior, float* __restrict__ rowmax) {
    int mb = blockIdx.x, rc = blockIdx.y;             // grid (24, 8)
    int tid = threadIdx.x;
    __shared__ float Ksh[64 * 132];                   // [k][c] padded (528B rows, 16B aligned)
    __shared__ float Qsh[16 * 64];
    for (int idx = tid; idx < 128 * 64; idx += 256) {
        int c = idx >> 6, k = idx & 63;
        Ksh[k * 132 + c] = Kh[((size_t)mb * 128 + c) * 64 + k];
    }
    for (int idx = tid; idx < 16 * 64; idx += 256) {
        int r = idx >> 6, k = idx & 63;
        Qsh[idx] = Qh[((size_t)mb * 128 + rc * 16 + r) * 64 + k];
    }
    __syncthreads();
    int rloc = tid >> 4, cg = tid & 15;
    float acc[8] = {};
    for (int k = 0; k < 64; ++k) {
        float qv = Qsh[rloc * 64 + k];
        const float* kr = &Ksh[k * 132 + cg * 8];
#pragma unroll
        for (int j = 0; j < 8; ++j) acc[j] += qv * kr[j];
    }
    float pm = -3.4e38f;
#pragma unroll
    for (int j = 0; j < 8; ++j) { acc[j] *= 0.125f; pm = fmaxf(pm, acc[j]); }
#pragma unroll
    for (int d = 1; d < 16; d <<= 1) pm = fmaxf(pm, __shfl_xor(pm, d, 64));
    int r = rc * 16 + rloc;
    if (cg == 0) rowmax[mb * 128 + r] = pm;
    float* dst = prior + ((size_t)mb * 128 + r) * 128 + cg * 8;
#pragma unroll
    for (int j = 0; j < 8; ++j) dst[j] = acc[j] - pm;
}

// ---------------- exact top-1024 threshold (radix select) + list build ----------------
__global__ __launch_bounds__(256)
void k_select(const float* __restrict__ prior, unsigned char* __restrict__ selmask,
              unsigned short* __restrict__ lists, int* __restrict__ counts) {
    int mb = blockIdx.x, tid = threadIdx.x;
    __shared__ int hist[256];
    __shared__ uint sh_pref;
    __shared__ int sh_k;
    __shared__ int cnt[128];
    if (tid == 0) { sh_pref = 0u; sh_k = 1024; }
    const float* P = prior + (size_t)mb * 16384;
    for (int lvl = 24; lvl >= 0; lvl -= 8) {
        hist[tid] = 0;
        __syncthreads();
        uint pref = sh_pref;
        uint maskAbove = (lvl == 24) ? 0u : (0xFFFFFFFFu << (lvl + 8));
        for (int idx = tid; idx < 16384; idx += 256) {
            int r = idx >> 7, c = idx & 127;
            float v = P[idx] + ((r - c <= 1 && c - r <= 1) ? 5e3f : 0.f);
            uint s = sortable(v);
            if ((s & maskAbove) == (pref & maskAbove))
                atomicAdd(&hist[(s >> lvl) & 255], 1);
        }
        __syncthreads();
        if (tid == 0) {
            int above = 0, k = sh_k, b = 255;
            for (; b > 0; --b) {
                int h = hist[b];
                if (above + h >= k) break;
                above += h;
            }
            sh_pref = pref | ((uint)b << lvl);
            sh_k = k - above;
        }
        __syncthreads();
    }
    uint T = sh_pref;                                  // bit pattern of 1024th-largest prior
    if (tid < 128) cnt[tid] = 0;
    __syncthreads();
    for (int idx = tid; idx < 16384; idx += 256) {
        int r = idx >> 7, c = idx & 127;
        float v = P[idx] + ((r - c <= 1 && c - r <= 1) ? 5e3f : 0.f);
        bool sel = sortable(v) >= T;
        selmask[(size_t)mb * 16384 + idx] = sel ? 1 : 0;
        if (sel) {
            int pos = atomicAdd(&cnt[r], 1);
            lists[((size_t)mb * 128 + r) * 128 + pos] = (unsigned short)c;
        }
    }
    __syncthreads();
    if (tid < 128) counts[mb * 128 + tid] = cnt[tid];
}

// ---------------- high-res sparse attention: one wave per (mb, q-block) ----------------
__global__ __launch_bounds__(64)
void k_high(const bf16* __restrict__ Qb, const bf16* __restrict__ Kb,
            const bf16* __restrict__ Vt, const int* __restrict__ counts,
            const unsigned short* __restrict__ lists,
            float* __restrict__ high_out, float* __restrict__ high_norm,
            float* __restrict__ max_vals) {
    const int q = blockIdx.x & 127, mb = blockIdx.x >> 7;
    const int lane = threadIdx.x, quad = lane >> 4, l16 = lane & 15;
    __shared__ bf16 Pb[32 * 40];                       // stride 40 keeps 16B alignment, breaks conflicts

    const bf16* Qbase = Qb + ((size_t)mb * 4096 + q * 32) * 64;
    bf16x8 qf[2][2];
#pragma unroll
    for (int mt = 0; mt < 2; ++mt)
#pragma unroll
        for (int ks = 0; ks < 2; ++ks)
            qf[mt][ks] = *(const bf16x8*)(Qbase + (mt * 16 + l16) * 64 + ks * 32 + quad * 8);

    float m_st[2][4], l_st[2][4];
    f32x4 o[2][4] = {};
#pragma unroll
    for (int mt = 0; mt < 2; ++mt)
#pragma unroll
        for (int r = 0; r < 4; ++r) { m_st[mt][r] = -1e30f; l_st[mt][r] = 0.f; }

    int cntv = counts[mb * 128 + q];
    if (cntv > 128) cntv = 128;
    const unsigned short* lst = lists + ((size_t)mb * 128 + q) * 128;

    for (int i = 0; i < cntv; ++i) {
        const int c = lst[i];
        const bf16* Kbase = Kb + ((size_t)mb * 4096 + c * 32) * 64;
        bf16x8 kf[2][2];
#pragma unroll
        for (int nt = 0; nt < 2; ++nt)
#pragma unroll
            for (int ks = 0; ks < 2; ++ks)
                kf[nt][ks] = *(const bf16x8*)(Kbase + (nt * 16 + l16) * 64 + ks * 32 + quad * 8);

        f32x4 sf[2][2] = {};
#pragma unroll
        for (int mt = 0; mt < 2; ++mt)
#pragma unroll
            for (int nt = 0; nt < 2; ++nt) {
                sf[mt][nt] = __builtin_amdgcn_mfma_f32_16x16x32_bf16(qf[mt][0], kf[nt][0], sf[mt][nt], 0, 0, 0);
                sf[mt][nt] = __builtin_amdgcn_mfma_f32_16x16x32_bf16(qf[mt][1], kf[nt][1], sf[mt][nt], 0, 0, 0);
                sf[mt][nt] *= 0.125f;
            }

        float rmx[2][4];
#pragma unroll
        for (int mt = 0; mt < 2; ++mt)
#pragma unroll
            for (int r = 0; r < 4; ++r)
                rmx[mt][r] = fmaxf(sf[mt][0][r], sf[mt][1][r]);
#pragma unroll
        for (int d = 1; d < 16; d <<= 1)
#pragma unroll
            for (int mt = 0; mt < 2; ++mt)
#pragma unroll
                for (int r = 0; r < 4; ++r)
                    rmx[mt][r] = fmaxf(rmx[mt][r], __shfl_xor(rmx[mt][r], d, 64));

        float alpha[2][4], rs[2][4];
#pragma unroll
        for (int mt = 0; mt < 2; ++mt)
#pragma unroll
            for (int r = 0; r < 4; ++r) {
                float mn = fmaxf(m_st[mt][r], rmx[mt][r]);
                alpha[mt][r] = __expf(m_st[mt][r] - mn);
                m_st[mt][r] = mn;
                rs[mt][r] = 0.f;
            }
#pragma unroll
        for (int mt = 0; mt < 2; ++mt)
#pragma unroll
            for (int nt = 0; nt < 2; ++nt)
#pragma unroll
                for (int r = 0; r < 4; ++r) {
                    float p = __expf(sf[mt][nt][r] - m_st[mt][r]);
                    rs[mt][r] += p;
                    Pb[(mt * 16 + quad * 4 + r) * 40 + nt * 16 + l16] = (bf16)p;
                }
#pragma unroll
        for (int d = 1; d < 16; d <<= 1)
#pragma unroll
            for (int mt = 0; mt < 2; ++mt)
#pragma unroll
                for (int r = 0; r < 4; ++r)
                    rs[mt][r] += __shfl_xor(rs[mt][r], d, 64);
#pragma unroll
        for (int mt = 0; mt < 2; ++mt)
#pragma unroll
            for (int r = 0; r < 4; ++r)
                l_st[mt][r] = l_st[mt][r] * alpha[mt][r] + rs[mt][r];
#pragma unroll
        for (int mt = 0; mt < 2; ++mt)
#pragma unroll
            for (int nd = 0; nd < 4; ++nd)
#pragma unroll
                for (int r = 0; r < 4; ++r)
                    o[mt][nd][r] *= alpha[mt][r];

        __syncthreads();                               // Pb writes -> A-frag reads (1 wave)
        bf16x8 pf[2];
#pragma unroll
        for (int mt = 0; mt < 2; ++mt)
            pf[mt] = *(const bf16x8*)&Pb[(mt * 16 + l16) * 40 + quad * 8];
        const bf16* Vbase = Vt + ((size_t)mb * 128 + c) * 2048;
        bf16x8 vf[4];
#pragma unroll
        for (int nd = 0; nd < 4; ++nd)
            vf[nd] = *(const bf16x8*)(Vbase + (nd * 16 + l16) * 32 + quad * 8);
#pragma unroll
        for (int mt = 0; mt < 2; ++mt)
#pragma unroll
            for (int nd = 0; nd < 4; ++nd)
                o[mt][nd] = __builtin_amdgcn_mfma_f32_16x16x32_bf16(pf[mt], vf[nd], o[mt][nd], 0, 0, 0);
        __syncthreads();
    }

    float* HO = high_out + ((size_t)mb * 4096 + q * 32) * 64;
#pragma unroll
    for (int mt = 0; mt < 2; ++mt)
#pragma unroll
        for (int nd = 0; nd < 4; ++nd)
#pragma unroll
            for (int r = 0; r < 4; ++r)
                HO[(mt * 16 + quad * 4 + r) * 64 + nd * 16 + l16] = o[mt][nd][r];
    if (l16 == 0) {
#pragma unroll
        for (int mt = 0; mt < 2; ++mt)
#pragma unroll
            for (int r = 0; r < 4; ++r) {
                int row = q * 32 + mt * 16 + quad * 4 + r;
                high_norm[(size_t)mb * 4096 + row] = l_st[mt][r];
                max_vals[(size_t)mb * 4096 + row] = fmaxf(m_st[mt][r], -1e6f);
            }
    }
}

// ---------------- low-res attention over non-selected blocks ----------------
__global__ __launch_bounds__(64)
void k_lowout(const float* __restrict__ prior, const unsigned char* __restrict__ selmask,
              const float* __restrict__ tc, const float* __restrict__ Vh,
              float* __restrict__ low_out, float* __restrict__ low_norm) {
    const int q = blockIdx.x & 127, mb = blockIdx.x >> 7;
    const int d = threadIdx.x;
    const float* pn = prior + ((size_t)mb * 128 + q) * 128;
    const unsigned char* sm = selmask + ((size_t)mb * 128 + q) * 128;
    const float* tcb = tc + (mb / 12) * 128;
    const float* Vb = Vh + (size_t)mb * 128 * 64;
    float acc = 0.f, nrm = 0.f;
    for (int c = 0; c < 128; ++c) {
        if (!sm[c]) {
            float w = __expf(pn[c]) * tcb[c];
            acc += w * Vb[c * 64 + d];
            nrm += w;
        }
    }
    low_out[((size_t)mb * 128 + q) * 64 + d] = acc;
    if (d == 0) low_norm[mb * 128 + q] = nrm;
}

// ---------------- final combine ----------------
__global__ __launch_bounds__(256)
void k_combine(const float* __restrict__ high_out, const float* __restrict__ high_norm,
               const float* __restrict__ max_vals, const float* __restrict__ low_out,
               const float* __restrict__ low_norm, const float* __restrict__ rowmax,
               const float* __restrict__ mask, float* __restrict__ out) {
    int gid = blockIdx.x * 256 + threadIdx.x;          // over 24*4096*64
    if (gid >= 6291456) return;
    int d = gid & 63;
    int s = (gid >> 6) & 4095;
    int mb = gid >> 18;
    int b = mb / 12, h = mb - b * 12;
    int q = s >> 5;
    float ho = high_out[gid];
    float hn = high_norm[(mb << 12) + s];
    float mv = max_vals[(mb << 12) + s];
    float rm = rowmax[mb * 128 + q];
    float lo = low_out[((size_t)mb * 128 + q) * 64 + d];
    float ln = low_norm[mb * 128 + q];
    float mk = mask[(b << 12) + s];
    float lcr = (rm - mv) * mk;
    float lcf = __expf(fminf(lcr, 0.f));
    float hcf = __expf(-fmaxf(lcr, 0.f));
    float val = (ho * hcf + lo * lcf) / (hn * hcf + ln * lcf + 1e-6f);
    out[((size_t)(b * 4096 + s)) * 768 + h * 64 + d] = val;
}

extern "C" void kernel_launch(void* const* d_in, const int* in_sizes, int n_in,
                              void* d_out, int out_size, void* d_ws, size_t ws_size,
                              hipStream_t stream) {
    (void)in_sizes; (void)n_in; (void)out_size; (void)ws_size;
    const float* X    = (const float*)d_in[0];
    const float* mask = (const float*)d_in[1];
    const float* Wq   = (const float*)d_in[2];
    const float* bq   = (const float*)d_in[3];
    const float* Wk   = (const float*)d_in[4];
    const float* bk   = (const float*)d_in[5];
    const float* Wv   = (const float*)d_in[6];
    const float* bv   = (const float*)d_in[7];
    float* out = (float*)d_out;

    char* ws = (char*)d_ws;
    size_t off = 0;
    auto alloc = [&](size_t bytes) -> void* {
        off = (off + 255) & ~(size_t)255;
        void* p = ws + off;
        off += bytes;
        return p;
    };
    bf16* Xb  = (bf16*)alloc((size_t)8192 * 768 * 2);
    bf16* Wb  = (bf16*)alloc((size_t)2304 * 768 * 2);
    bf16* Qb  = (bf16*)alloc((size_t)24 * 4096 * 64 * 2);
    bf16* Kb  = (bf16*)alloc((size_t)24 * 4096 * 64 * 2);
    bf16* Vt  = (bf16*)alloc((size_t)24 * 4096 * 64 * 2);
    float* Xh = (float*)alloc((size_t)256 * 768 * 4);
    float* tc = (float*)alloc(256 * 4);
    float* Qh = (float*)alloc((size_t)24 * 128 * 64 * 4);
    float* Kh = (float*)alloc((size_t)24 * 128 * 64 * 4);
    float* Vh = (float*)alloc((size_t)24 * 128 * 64 * 4);
    float* prior = (float*)alloc((size_t)24 * 16384 * 4);
    float* rowmax = (float*)alloc(24 * 128 * 4);
    unsigned char* selmask = (unsigned char*)alloc((size_t)24 * 16384);
    unsigned short* lists = (unsigned short*)alloc((size_t)24 * 128 * 128 * 2);
    int* counts = (int*)alloc(24 * 128 * 4);
    float* high_out  = (float*)alloc((size_t)24 * 4096 * 64 * 4);
    float* high_norm = (float*)alloc((size_t)24 * 4096 * 4);
    float* max_vals  = (float*)alloc((size_t)24 * 4096 * 4);
    float* low_out   = (float*)alloc((size_t)24 * 128 * 64 * 4);
    float* low_norm  = (float*)alloc(24 * 128 * 4);

    k_convX<<<6144, 256, 0, stream>>>(X, Xb);
    k_convW<<<1728, 256, 0, stream>>>(Wq, Wk, Wv, Wb);
    k_xhsum<<<192, 256, 0, stream>>>(X, mask, Xh);
    k_tc<<<1, 256, 0, stream>>>(mask, tc);
    k_gemm_qkv<<<dim3(64, 18), 256, 0, stream>>>(Xb, Wb, bq, bk, bv, mask, Qb, Kb, Vt);
    k_lowres<<<dim3(9, 32), 256, 0, stream>>>(Xh, tc, Wq, Wk, Wv, bq, bk, bv, Qh, Kh, Vh);
    k_lowlogit<<<dim3(24, 8), 256, 0, stream>>>(Qh, Kh, prior, rowmax);
    k_select<<<24, 256, 0, stream>>>(prior, selmask, lists, counts);
    k_high<<<3072, 64, 0, stream>>>(Qb, Kb, Vt, counts, lists, high_out, high_norm, max_vals);
    k_lowout<<<3072, 64, 0, stream>>>(prior, selmask, tc, Vh, low_out, low_norm);
    k_combine<<<24576, 256, 0, stream>>>(high_out, high_norm, max_vals, low_out, low_norm,
                                         rowmax, mask, out);
}

// Round 3
// 379.264 us; speedup vs baseline: 1.1617x; 1.1617x over previous
//
#include <hip/hip_runtime.h>

typedef __bf16 bf16;
typedef float f32x4 __attribute__((ext_vector_type(4)));
typedef bf16 bf16x8 __attribute__((ext_vector_type(8)));
typedef bf16 bf16x4 __attribute__((ext_vector_type(4)));
typedef unsigned int uint;

// Problem constants: B=2 S=4096 D=768 H=12 HD=64 BLK=32 NBR=128 MB=24 NUM_BLOCK=1024 DIAG_N=3

__device__ __forceinline__ void llds16(const bf16* g, bf16* l) {
    __builtin_amdgcn_global_load_lds((const __attribute__((address_space(1))) uint*)g,
                                     (__attribute__((address_space(3))) uint*)l, 16, 0, 0);
}

__device__ __forceinline__ uint sortable(float f) {
    uint u = __float_as_uint(f);
    return u ^ (uint)(((int)u >> 31) | 0x80000000);
}

// ---------------- prep: conversions / block sums ----------------
__global__ void k_convX(const float* __restrict__ X, bf16* __restrict__ Xb) {
    int i = blockIdx.x * 256 + threadIdx.x;          // over 8192*768/4
    if (i >= 1572864) return;
    float4 f = ((const float4*)X)[i];
    bf16x4 o = {(bf16)f.x, (bf16)f.y, (bf16)f.z, (bf16)f.w};
    ((bf16x4*)Xb)[i] = o;
}

__global__ void k_convW(const float* __restrict__ Wq, const float* __restrict__ Wk,
                        const float* __restrict__ Wv, bf16* __restrict__ Wb) {
    int i = blockIdx.x * 256 + threadIdx.x;          // over 2304*768/4
    if (i >= 442368) return;
    int n = (i << 2) / 768;
    int k = (i << 2) % 768;
    const float* W = n < 768 ? Wq : (n < 1536 ? Wk : Wv);
    int nn = n - (n < 768 ? 0 : (n < 1536 ? 768 : 1536));
    float4 f = *(const float4*)(W + (size_t)nn * 768 + k);
    bf16x4 o = {(bf16)f.x, (bf16)f.y, (bf16)f.z, (bf16)f.w};
    ((bf16x4*)Wb)[i] = o;
}

__global__ void k_xhsum(const float* __restrict__ X, const float* __restrict__ mask,
                        float* __restrict__ Xh) {
    int gid = blockIdx.x * 256 + threadIdx.x;        // over 256*192 (rows x float4-cols)
    if (gid >= 256 * 192) return;
    int c4 = gid % 192, row = gid / 192;             // row = b*128 + nbr
    int b = row >> 7, nbr = row & 127;
    const float4* xp = (const float4*)(X + ((size_t)(b * 4096 + nbr * 32)) * 768) + c4;
    const float* mp = mask + b * 4096 + nbr * 32;
    float4 s = {0.f, 0.f, 0.f, 0.f};
    for (int t = 0; t < 32; ++t) {
        float4 v = xp[(size_t)t * 192];
        float m = mp[t];
        s.x += v.x * m; s.y += v.y * m; s.z += v.z * m; s.w += v.w * m;
    }
    *((float4*)(Xh + (size_t)row * 768) + c4) = s;
}

__global__ void k_tc(const float* __restrict__ mask, float* __restrict__ tc) {
    int i = threadIdx.x;                              // 256 = B*NBR
    int b = i >> 7, nbr = i & 127;
    float s = 0.f;
    for (int t = 0; t < 32; ++t) s += mask[b * 4096 + nbr * 32 + t];
    tc[i] = s;
}

// ---------------- QKV projection GEMM (bf16 MFMA, m97 structure) ----------------
// Y[8192 x 2304] = Xb[8192x768] @ Wb[2304x768]^T + bias, epilogue scatters into
// Q/K [mb][s][d] bf16 and V transposed [mb][nb][d][t] bf16 (for PV B-fragments).
__global__ __launch_bounds__(256)
void k_gemm_qkv(const bf16* __restrict__ Xb, const bf16* __restrict__ Wb,
                const float* __restrict__ bq, const float* __restrict__ bk,
                const float* __restrict__ bv, const float* __restrict__ mask,
                bf16* __restrict__ Qb, bf16* __restrict__ Kb, bf16* __restrict__ Vt) {
    __shared__ bf16 As[128 * 32];
    __shared__ bf16 Bs[128 * 32];
    const int tid = threadIdx.x;
    const int wave = tid >> 6, lane = tid & 63;
    const int quad = lane >> 4, l16 = lane & 15;
    const int wr = wave >> 1, wc = wave & 1;
    const int m0 = blockIdx.x * 128, n0 = blockIdx.y * 128;
    const int sr = lane >> 2, sc = (lane & 3) * 8;

    f32x4 acc[4][4] = {};

    for (int k0 = 0; k0 < 768; k0 += 32) {
        __syncthreads();
#pragma unroll
        for (int it = 0; it < 2; ++it) {
            int rbase = wave * 32 + it * 16;
            llds16(Xb + (size_t)(m0 + rbase + sr) * 768 + k0 + sc, &As[rbase * 32]);
            llds16(Wb + (size_t)(n0 + rbase + sr) * 768 + k0 + sc, &Bs[rbase * 32]);
        }
        __syncthreads();
        bf16x8 a[4], b[4];
#pragma unroll
        for (int i = 0; i < 4; ++i)
            a[i] = *(const bf16x8*)&As[(wr * 64 + i * 16 + l16) * 32 + quad * 8];
#pragma unroll
        for (int i = 0; i < 4; ++i)
            b[i] = *(const bf16x8*)&Bs[(wc * 64 + i * 16 + l16) * 32 + quad * 8];
#pragma unroll
        for (int i = 0; i < 4; ++i)
#pragma unroll
            for (int j = 0; j < 4; ++j)
                acc[i][j] = __builtin_amdgcn_mfma_f32_16x16x32_bf16(a[i], b[j], acc[i][j], 0, 0, 0);
    }

    const int which = n0 / 768;                       // uniform per block
    const float* bias = which == 0 ? bq : (which == 1 ? bk : bv);
#pragma unroll
    for (int i = 0; i < 4; ++i) {
        int mrow = m0 + wr * 64 + i * 16 + quad * 4;
#pragma unroll
        for (int j = 0; j < 4; ++j) {
            int n = n0 + wc * 64 + j * 16 + l16;
            int hcol = n - which * 768;
            int h = hcol >> 6, d = hcol & 63;
#pragma unroll
            for (int r = 0; r < 4; ++r) {
                int mm = mrow + r;
                int bidx = mm >> 12, s = mm & 4095;
                float y = (acc[i][j][r] + bias[hcol]) * mask[(bidx << 12) + s];
                bf16 v = (bf16)y;
                size_t mb = (size_t)(bidx * 12 + h);
                if (which == 0)      Qb[((mb << 12) + s) * 64 + d] = v;
                else if (which == 1) Kb[((mb << 12) + s) * 64 + d] = v;
                else                 Vt[((mb * 128 + (s >> 5)) * 64 + d) * 32 + (s & 31)] = v;
            }
        }
    }
}

// ---------------- exact f32 low-res projections: Qh/Kh/Vh ----------------
// Qh[mb][nb][d] = (Xh_sum[b][nb] @ W^T + tc*b) / (tc + 1e-6)
__global__ __launch_bounds__(256)
void k_lowres(const float* __restrict__ Xh, const float* __restrict__ tc,
              const float* __restrict__ Wq, const float* __restrict__ Wk,
              const float* __restrict__ Wv, const float* __restrict__ bq,
              const float* __restrict__ bk, const float* __restrict__ bv,
              float* __restrict__ Qh, float* __restrict__ Kh, float* __restrict__ Vh) {
    int nb9 = blockIdx.x, rc = blockIdx.y, t = threadIdx.x;   // grid (9, 32)
    __shared__ float xsh[8 * 768];
    for (int idx = t; idx < 8 * 768; idx += 256)
        xsh[idx] = Xh[(size_t)(rc * 8) * 768 + idx];
    __syncthreads();
    int which = nb9 / 3;
    int wcol = (nb9 % 3) * 256 + t;
    const float* W = (which == 0 ? Wq : (which == 1 ? Wk : Wv)) + (size_t)wcol * 768;
    const float* bias = which == 0 ? bq : (which == 1 ? bk : bv);
    float acc[8] = {};
    for (int k = 0; k < 768; k += 4) {
        float4 w4 = *(const float4*)(W + k);
#pragma unroll
        for (int j = 0; j < 8; ++j) {
            float4 x4 = *(const float4*)&xsh[j * 768 + k];
            acc[j] += w4.x * x4.x + w4.y * x4.y + w4.z * x4.z + w4.w * x4.w;
        }
    }
    int h = wcol >> 6, d = wcol & 63;
    float bval = bias[wcol];
    float* dst = which == 0 ? Qh : (which == 1 ? Kh : Vh);
#pragma unroll
    for (int j = 0; j < 8; ++j) {
        int row = rc * 8 + j;
        int b = row >> 7, nbr = row & 127;
        float tcv = tc[row];
        float val = (acc[j] + tcv * bval) / (tcv + 1e-6f);
        dst[(((size_t)(b * 12 + h)) * 128 + nbr) * 64 + d] = val;
    }
}

// ---------------- low-res logits + row max (f32 exact) ----------------
__global__ __launch_bounds__(256)
void k_lowlogit(const float* __restrict__ Qh, const float* __restrict__ Kh,
                float* __restrict__ prior, float* __restrict__ rowmax) {
    int mb = blockIdx.x, rc = blockIdx.y;             // grid (24, 8)
    int tid = threadIdx.x;
    __shared__ float Ksh[64 * 132];                   // [k][c] padded (528B rows, 16B aligned)
    __shared__ float Qsh[16 * 64];
    for (int idx = tid; idx < 128 * 64; idx += 256) {
        int c = idx >> 6, k = idx & 63;
        Ksh[k * 132 + c] = Kh[((size_t)mb * 128 + c) * 64 + k];
    }
    for (int idx = tid; idx < 16 * 64; idx += 256) {
        int r = idx >> 6, k = idx & 63;
        Qsh[idx] = Qh[((size_t)mb * 128 + rc * 16 + r) * 64 + k];
    }
    __syncthreads();
    int rloc = tid >> 4, cg = tid & 15;
    float acc[8] = {};
    for (int k = 0; k < 64; ++k) {
        float qv = Qsh[rloc * 64 + k];
        const float* kr = &Ksh[k * 132 + cg * 8];
#pragma unroll
        for (int j = 0; j < 8; ++j) acc[j] += qv * kr[j];
    }
    float pm = -3.4e38f;
#pragma unroll
    for (int j = 0; j < 8; ++j) { acc[j] *= 0.125f; pm = fmaxf(pm, acc[j]); }
#pragma unroll
    for (int d = 1; d < 16; d <<= 1) pm = fmaxf(pm, __shfl_xor(pm, d, 64));
    int r = rc * 16 + rloc;
    if (cg == 0) rowmax[mb * 128 + r] = pm;
    float* dst = prior + ((size_t)mb * 128 + r) * 128 + cg * 8;
#pragma unroll
    for (int j = 0; j < 8; ++j) dst[j] = acc[j] - pm;
}

// ---------------- exact top-1024 threshold + list build ----------------
// R2 rewrite: 2-bit-per-level MSB radix descent (16 levels). Keys in registers.
// Per level: per-thread VALU counts -> wave shfl_xor reduce -> lane0 atomicAdd
// into that level's preallocated LDS slots -> one barrier -> every thread
// redundantly replays the (prefix, k) decision from the shared counts.
// No waterfall/ballot idiom, no data-dependent-address atomics.
__global__ __launch_bounds__(1024)
void k_select(const float* __restrict__ prior, unsigned char* __restrict__ selmask,
              unsigned short* __restrict__ lists, int* __restrict__ counts) {
    const int mb = blockIdx.x, tid = threadIdx.x;
    const int ln = tid & 63;
    __shared__ int lc[16 * 3];                 // [level][field 3,2,1] counts
    __shared__ int cnt[128];
    if (tid < 48) lc[tid] = 0;
    if (tid < 128) cnt[tid] = 0;

    // each thread owns 16 consecutive elements of one row: flat idx = tid*16 + j
    const int r = tid >> 3;                    // row (q-block) index, 8 threads/row
    const int cbase = (tid & 7) << 4;          // starting column
    uint key[16];
    const float4* P4 = (const float4*)(prior + (size_t)mb * 16384) + (tid << 2);
#pragma unroll
    for (int j4 = 0; j4 < 4; ++j4) {
        float4 v = P4[j4];
        float vv[4] = {v.x, v.y, v.z, v.w};
#pragma unroll
        for (int e = 0; e < 4; ++e) {
            int c = cbase + (j4 << 2) + e;
            float f = vv[e] + ((r - c <= 1 && c - r <= 1) ? 5e3f : 0.f);
            key[(j4 << 2) + e] = sortable(f);
        }
    }
    __syncthreads();                           // lc/cnt zeroed before use

    uint pfx = 0u;                             // redundant per-thread state
    int k = 1024;
#pragma unroll
    for (int lvl = 0; lvl < 16; ++lvl) {
        const int sh = 30 - 2 * lvl;
        const uint maskA = (lvl == 0) ? 0u : (0xFFFFFFFFu << (sh + 2));
        int c3 = 0, c2 = 0, c1 = 0;
#pragma unroll
        for (int j = 0; j < 16; ++j) {
            uint x = key[j];
            bool m = ((x ^ pfx) & maskA) == 0u;
            uint f = (x >> sh) & 3u;
            c3 += (m && f == 3u);
            c2 += (m && f == 2u);
            c1 += (m && f == 1u);
        }
#pragma unroll
        for (int d = 1; d < 64; d <<= 1) {
            c3 += __shfl_xor(c3, d, 64);
            c2 += __shfl_xor(c2, d, 64);
            c1 += __shfl_xor(c1, d, 64);
        }
        if (ln == 0) {
            atomicAdd(&lc[lvl * 3 + 0], c3);
            atomicAdd(&lc[lvl * 3 + 1], c2);
            atomicAdd(&lc[lvl * 3 + 2], c1);
        }
        __syncthreads();
        const int C3 = lc[lvl * 3 + 0], C2 = lc[lvl * 3 + 1], C1 = lc[lvl * 3 + 2];
        uint choose;
        if (C3 >= k)                { choose = 3u; }
        else if (C3 + C2 >= k)      { choose = 2u; k -= C3; }
        else if (C3 + C2 + C1 >= k) { choose = 1u; k -= C3 + C2; }
        else                        { choose = 0u; k -= C3 + C2 + C1; }
        pfx |= choose << sh;
    }
    const uint T = pfx;                        // exact bit pattern of 1024th-largest prior

    uint packed[4] = {0u, 0u, 0u, 0u};
#pragma unroll
    for (int j = 0; j < 16; ++j) {
        if (key[j] >= T) {
            packed[j >> 2] |= 1u << ((j & 3) << 3);
            int pos = atomicAdd(&cnt[r], 1);
            lists[((size_t)mb * 128 + r) * 128 + pos] = (unsigned short)(cbase + j);
        }
    }
    uint4 pk;
    pk.x = packed[0]; pk.y = packed[1]; pk.z = packed[2]; pk.w = packed[3];
    *(uint4*)(selmask + (size_t)mb * 16384 + (size_t)tid * 16) = pk;
    __syncthreads();
    if (tid < 128) counts[mb * 128 + tid] = cnt[tid];
}

// ---------------- high-res sparse attention: one wave per (mb, q-block) ----------------
__global__ __launch_bounds__(64)
void k_high(const bf16* __restrict__ Qb, const bf16* __restrict__ Kb,
            const bf16* __restrict__ Vt, const int* __restrict__ counts,
            const unsigned short* __restrict__ lists,
            float* __restrict__ high_out, float* __restrict__ high_norm,
            float* __restrict__ max_vals) {
    const int q = blockIdx.x & 127, mb = blockIdx.x >> 7;
    const int lane = threadIdx.x, quad = lane >> 4, l16 = lane & 15;
    __shared__ bf16 Pb[32 * 40];                       // stride 40 keeps 16B alignment, breaks conflicts

    const bf16* Qbase = Qb + ((size_t)mb * 4096 + q * 32) * 64;
    bf16x8 qf[2][2];
#pragma unroll
    for (int mt = 0; mt < 2; ++mt)
#pragma unroll
        for (int ks = 0; ks < 2; ++ks)
            qf[mt][ks] = *(const bf16x8*)(Qbase + (mt * 16 + l16) * 64 + ks * 32 + quad * 8);

    float m_st[2][4], l_st[2][4];
    f32x4 o[2][4] = {};
#pragma unroll
    for (int mt = 0; mt < 2; ++mt)
#pragma unroll
        for (int r = 0; r < 4; ++r) { m_st[mt][r] = -1e30f; l_st[mt][r] = 0.f; }

    int cntv = counts[mb * 128 + q];
    if (cntv > 128) cntv = 128;
    const unsigned short* lst = lists + ((size_t)mb * 128 + q) * 128;

    for (int i = 0; i < cntv; ++i) {
        const int c = lst[i];
        const bf16* Kbase = Kb + ((size_t)mb * 4096 + c * 32) * 64;
        bf16x8 kf[2][2];
#pragma unroll
        for (int nt = 0; nt < 2; ++nt)
#pragma unroll
            for (int ks = 0; ks < 2; ++ks)
                kf[nt][ks] = *(const bf16x8*)(Kbase + (nt * 16 + l16) * 64 + ks * 32 + quad * 8);

        f32x4 sf[2][2] = {};
#pragma unroll
        for (int mt = 0; mt < 2; ++mt)
#pragma unroll
            for (int nt = 0; nt < 2; ++nt) {
                sf[mt][nt] = __builtin_amdgcn_mfma_f32_16x16x32_bf16(qf[mt][0], kf[nt][0], sf[mt][nt], 0, 0, 0);
                sf[mt][nt] = __builtin_amdgcn_mfma_f32_16x16x32_bf16(qf[mt][1], kf[nt][1], sf[mt][nt], 0, 0, 0);
                sf[mt][nt] *= 0.125f;
            }

        float rmx[2][4];
#pragma unroll
        for (int mt = 0; mt < 2; ++mt)
#pragma unroll
            for (int r = 0; r < 4; ++r)
                rmx[mt][r] = fmaxf(sf[mt][0][r], sf[mt][1][r]);
#pragma unroll
        for (int d = 1; d < 16; d <<= 1)
#pragma unroll
            for (int mt = 0; mt < 2; ++mt)
#pragma unroll
                for (int r = 0; r < 4; ++r)
                    rmx[mt][r] = fmaxf(rmx[mt][r], __shfl_xor(rmx[mt][r], d, 64));

        float alpha[2][4], rs[2][4];
#pragma unroll
        for (int mt = 0; mt < 2; ++mt)
#pragma unroll
            for (int r = 0; r < 4; ++r) {
                float mn = fmaxf(m_st[mt][r], rmx[mt][r]);
                alpha[mt][r] = __expf(m_st[mt][r] - mn);
                m_st[mt][r] = mn;
                rs[mt][r] = 0.f;
            }
#pragma unroll
        for (int mt = 0; mt < 2; ++mt)
#pragma unroll
            for (int nt = 0; nt < 2; ++nt)
#pragma unroll
                for (int r = 0; r < 4; ++r) {
                    float p = __expf(sf[mt][nt][r] - m_st[mt][r]);
                    rs[mt][r] += p;
                    Pb[(mt * 16 + quad * 4 + r) * 40 + nt * 16 + l16] = (bf16)p;
                }
#pragma unroll
        for (int d = 1; d < 16; d <<= 1)
#pragma unroll
            for (int mt = 0; mt < 2; ++mt)
#pragma unroll
                for (int r = 0; r < 4; ++r)
                    rs[mt][r] += __shfl_xor(rs[mt][r], d, 64);
#pragma unroll
        for (int mt = 0; mt < 2; ++mt)
#pragma unroll
            for (int r = 0; r < 4; ++r)
                l_st[mt][r] = l_st[mt][r] * alpha[mt][r] + rs[mt][r];
#pragma unroll
        for (int mt = 0; mt < 2; ++mt)
#pragma unroll
            for (int nd = 0; nd < 4; ++nd)
#pragma unroll
                for (int r = 0; r < 4; ++r)
                    o[mt][nd][r] *= alpha[mt][r];

        __syncthreads();                               // Pb writes -> A-frag reads (1 wave)
        bf16x8 pf[2];
#pragma unroll
        for (int mt = 0; mt < 2; ++mt)
            pf[mt] = *(const bf16x8*)&Pb[(mt * 16 + l16) * 40 + quad * 8];
        const bf16* Vbase = Vt + ((size_t)mb * 128 + c) * 2048;
        bf16x8 vf[4];
#pragma unroll
        for (int nd = 0; nd < 4; ++nd)
            vf[nd] = *(const bf16x8*)(Vbase + (nd * 16 + l16) * 32 + quad * 8);
#pragma unroll
        for (int mt = 0; mt < 2; ++mt)
#pragma unroll
            for (int nd = 0; nd < 4; ++nd)
                o[mt][nd] = __builtin_amdgcn_mfma_f32_16x16x32_bf16(pf[mt], vf[nd], o[mt][nd], 0, 0, 0);
        __syncthreads();
    }

    float* HO = high_out + ((size_t)mb * 4096 + q * 32) * 64;
#pragma unroll
    for (int mt = 0; mt < 2; ++mt)
#pragma unroll
        for (int nd = 0; nd < 4; ++nd)
#pragma unroll
            for (int r = 0; r < 4; ++r)
                HO[(mt * 16 + quad * 4 + r) * 64 + nd * 16 + l16] = o[mt][nd][r];
    if (l16 == 0) {
#pragma unroll
        for (int mt = 0; mt < 2; ++mt)
#pragma unroll
            for (int r = 0; r < 4; ++r) {
                int row = q * 32 + mt * 16 + quad * 4 + r;
                high_norm[(size_t)mb * 4096 + row] = l_st[mt][r];
                max_vals[(size_t)mb * 4096 + row] = fmaxf(m_st[mt][r], -1e6f);
            }
    }
}

// ---------------- low-res attention over non-selected blocks ----------------
__global__ __launch_bounds__(64)
void k_lowout(const float* __restrict__ prior, const unsigned char* __restrict__ selmask,
              const float* __restrict__ tc, const float* __restrict__ Vh,
              float* __restrict__ low_out, float* __restrict__ low_norm) {
    const int q = blockIdx.x & 127, mb = blockIdx.x >> 7;
    const int d = threadIdx.x;
    const float* pn = prior + ((size_t)mb * 128 + q) * 128;
    const unsigned char* sm = selmask + ((size_t)mb * 128 + q) * 128;
    const float* tcb = tc + (mb / 12) * 128;
    const float* Vb = Vh + (size_t)mb * 128 * 64;
    float acc = 0.f, nrm = 0.f;
    for (int c = 0; c < 128; ++c) {
        if (!sm[c]) {
            float w = __expf(pn[c]) * tcb[c];
            acc += w * Vb[c * 64 + d];
            nrm += w;
        }
    }
    low_out[((size_t)mb * 128 + q) * 64 + d] = acc;
    if (d == 0) low_norm[mb * 128 + q] = nrm;
}

// ---------------- final combine ----------------
__global__ __launch_bounds__(256)
void k_combine(const float* __restrict__ high_out, const float* __restrict__ high_norm,
               const float* __restrict__ max_vals, const float* __restrict__ low_out,
               const float* __restrict__ low_norm, const float* __restrict__ rowmax,
               const float* __restrict__ mask, float* __restrict__ out) {
    int gid = blockIdx.x * 256 + threadIdx.x;          // over 24*4096*64
    if (gid >= 6291456) return;
    int d = gid & 63;
    int s = (gid >> 6) & 4095;
    int mb = gid >> 18;
    int b = mb / 12, h = mb - b * 12;
    int q = s >> 5;
    float ho = high_out[gid];
    float hn = high_norm[(mb << 12) + s];
    float mv = max_vals[(mb << 12) + s];
    float rm = rowmax[mb * 128 + q];
    float lo = low_out[((size_t)mb * 128 + q) * 64 + d];
    float ln = low_norm[mb * 128 + q];
    float mk = mask[(b << 12) + s];
    float lcr = (rm - mv) * mk;
    float lcf = __expf(fminf(lcr, 0.f));
    float hcf = __expf(-fmaxf(lcr, 0.f));
    float val = (ho * hcf + lo * lcf) / (hn * hcf + ln * lcf + 1e-6f);
    out[((size_t)(b * 4096 + s)) * 768 + h * 64 + d] = val;
}

extern "C" void kernel_launch(void* const* d_in, const int* in_sizes, int n_in,
                              void* d_out, int out_size, void* d_ws, size_t ws_size,
                              hipStream_t stream) {
    (void)in_sizes; (void)n_in; (void)out_size; (void)ws_size;
    const float* X    = (const float*)d_in[0];
    const float* mask = (const float*)d_in[1];
    const float* Wq   = (const float*)d_in[2];
    const float* bq   = (const float*)d_in[3];
    const float* Wk   = (const float*)d_in[4];
    const float* bk   = (const float*)d_in[5];
    const float* Wv   = (const float*)d_in[6];
    const float* bv   = (const float*)d_in[7];
    float* out = (float*)d_out;

    char* ws = (char*)d_ws;
    size_t off = 0;
    auto alloc = [&](size_t bytes) -> void* {
        off = (off + 255) & ~(size_t)255;
        void* p = ws + off;
        off += bytes;
        return p;
    };
    bf16* Xb  = (bf16*)alloc((size_t)8192 * 768 * 2);
    bf16* Wb  = (bf16*)alloc((size_t)2304 * 768 * 2);
    bf16* Qb  = (bf16*)alloc((size_t)24 * 4096 * 64 * 2);
    bf16* Kb  = (bf16*)alloc((size_t)24 * 4096 * 64 * 2);
    bf16* Vt  = (bf16*)alloc((size_t)24 * 4096 * 64 * 2);
    float* Xh = (float*)alloc((size_t)256 * 768 * 4);
    float* tc = (float*)alloc(256 * 4);
    float* Qh = (float*)alloc((size_t)24 * 128 * 64 * 4);
    float* Kh = (float*)alloc((size_t)24 * 128 * 64 * 4);
    float* Vh = (float*)alloc((size_t)24 * 128 * 64 * 4);
    float* prior = (float*)alloc((size_t)24 * 16384 * 4);
    float* rowmax = (float*)alloc(24 * 128 * 4);
    unsigned char* selmask = (unsigned char*)alloc((size_t)24 * 16384);
    unsigned short* lists = (unsigned short*)alloc((size_t)24 * 128 * 128 * 2);
    int* counts = (int*)alloc(24 * 128 * 4);
    float* high_out  = (float*)alloc((size_t)24 * 4096 * 64 * 4);
    float* high_norm = (float*)alloc((size_t)24 * 4096 * 4);
    float* max_vals  = (float*)alloc((size_t)24 * 4096 * 4);
    float* low_out   = (float*)alloc((size_t)24 * 128 * 64 * 4);
    float* low_norm  = (float*)alloc(24 * 128 * 4);

    k_convX<<<6144, 256, 0, stream>>>(X, Xb);
    k_convW<<<1728, 256, 0, stream>>>(Wq, Wk, Wv, Wb);
    k_xhsum<<<192, 256, 0, stream>>>(X, mask, Xh);
    k_tc<<<1, 256, 0, stream>>>(mask, tc);
    k_gemm_qkv<<<dim3(64, 18), 256, 0, stream>>>(Xb, Wb, bq, bk, bv, mask, Qb, Kb, Vt);
    k_lowres<<<dim3(9, 32), 256, 0, stream>>>(Xh, tc, Wq, Wk, Wv, bq, bk, bv, Qh, Kh, Vh);
    k_lowlogit<<<dim3(24, 8), 256, 0, stream>>>(Qh, Kh, prior, rowmax);
    k_select<<<24, 1024, 0, stream>>>(prior, selmask, lists, counts);
    k_high<<<3072, 64, 0, stream>>>(Qb, Kb, Vt, counts, lists, high_out, high_norm, max_vals);
    k_lowout<<<3072, 64, 0, stream>>>(prior, selmask, tc, Vh, low_out, low_norm);
    k_combine<<<24576, 256, 0, stream>>>(high_out, high_norm, max_vals, low_out, low_norm,
                                         rowmax, mask, out);
}

// Round 4
// 355.921 us; speedup vs baseline: 1.2379x; 1.0656x over previous
//
#include <hip/hip_runtime.h>

typedef __bf16 bf16;
typedef float f32x4 __attribute__((ext_vector_type(4)));
typedef bf16 bf16x8 __attribute__((ext_vector_type(8)));
typedef bf16 bf16x4 __attribute__((ext_vector_type(4)));
typedef unsigned int uint;

// Problem constants: B=2 S=4096 D=768 H=12 HD=64 BLK=32 NBR=128 MB=24 NUM_BLOCK=1024 DIAG_N=3

__device__ __forceinline__ void llds16(const bf16* g, bf16* l) {
    __builtin_amdgcn_global_load_lds((const __attribute__((address_space(1))) uint*)g,
                                     (__attribute__((address_space(3))) uint*)l, 16, 0, 0);
}

__device__ __forceinline__ uint sortable(float f) {
    uint u = __float_as_uint(f);
    return u ^ (uint)(((int)u >> 31) | 0x80000000);
}

// ---------------- fused prep: X->bf16 conversion + masked block sums + token counts ----
// One block per (b, nbr): reads 32x768 f32 once, writes bf16 copy, block-sum, tc.
__global__ __launch_bounds__(192)
void k_prep(const float* __restrict__ X, const float* __restrict__ mask,
            bf16* __restrict__ Xb, float* __restrict__ Xh, float* __restrict__ tc) {
    const int row = blockIdx.x;                 // b*128 + nbr
    const int b = row >> 7, nbr = row & 127;
    const int t = threadIdx.x;                  // float4 column 0..191
    const float4* xp = (const float4*)(X + (size_t)(b * 4096 + nbr * 32) * 768) + t;
    bf16x4* xbp = (bf16x4*)(Xb + (size_t)(b * 4096 + nbr * 32) * 768) + t;
    const float* mp = mask + b * 4096 + nbr * 32;
    float4 s = {0.f, 0.f, 0.f, 0.f};
    float tcs = 0.f;
#pragma unroll 4
    for (int tok = 0; tok < 32; ++tok) {
        float4 v = xp[(size_t)tok * 192];
        float m = mp[tok];
        s.x += v.x * m; s.y += v.y * m; s.z += v.z * m; s.w += v.w * m;
        tcs += m;
        bf16x4 o = {(bf16)v.x, (bf16)v.y, (bf16)v.z, (bf16)v.w};
        xbp[(size_t)tok * 192] = o;
    }
    ((float4*)(Xh + (size_t)row * 768))[t] = s;
    if (t == 0) tc[row] = tcs;
}

__global__ void k_convW(const float* __restrict__ Wq, const float* __restrict__ Wk,
                        const float* __restrict__ Wv, bf16* __restrict__ Wb) {
    int i = blockIdx.x * 256 + threadIdx.x;          // over 2304*768/4
    if (i >= 442368) return;
    int n = (i << 2) / 768;
    int k = (i << 2) % 768;
    const float* W = n < 768 ? Wq : (n < 1536 ? Wk : Wv);
    int nn = n - (n < 768 ? 0 : (n < 1536 ? 768 : 1536));
    float4 f = *(const float4*)(W + (size_t)nn * 768 + k);
    bf16x4 o = {(bf16)f.x, (bf16)f.y, (bf16)f.z, (bf16)f.w};
    ((bf16x4*)Wb)[i] = o;
}

// ---------------- QKV projection GEMM (bf16 MFMA, BK=64, XOR-swizzled LDS) ----------
// Y[8192 x 2304] = Xb[8192x768] @ Wb[2304x768]^T + bias, epilogue scatters into
// Q/K [mb][s][d] bf16 and V transposed [mb][nb][d][t] bf16 (for PV B-fragments).
// LDS logical (row, group g of 8 bf16) stored at physical group g^(row&7):
// staging lane ln sources global col-group (ln&7)^((ln>>3)&7) so that
// global_load_lds's base+lane*16 contiguity lands each row swizzled; fragment
// ds_read_b128 then hits all 32 banks across l16 (2-way aliasing only).
__global__ __launch_bounds__(256)
void k_gemm_qkv(const bf16* __restrict__ Xb, const bf16* __restrict__ Wb,
                const float* __restrict__ bq, const float* __restrict__ bk,
                const float* __restrict__ bv, const float* __restrict__ mask,
                bf16* __restrict__ Qb, bf16* __restrict__ Kb, bf16* __restrict__ Vt) {
    __shared__ bf16 As[128 * 64];
    __shared__ bf16 Bs[128 * 64];
    const int tid = threadIdx.x;
    const int wave = tid >> 6, lane = tid & 63;
    const int quad = lane >> 4, l16 = lane & 15;
    const int wr = wave >> 1, wc = wave & 1;
    const int m0 = blockIdx.x * 128, n0 = blockIdx.y * 128;
    const int srow = lane >> 3;                              // row within 8-row chunk
    const int sgcol = (((lane & 7) ^ (srow & 7)) << 3);      // swizzled source col

    f32x4 acc[4][4] = {};

    for (int k0 = 0; k0 < 768; k0 += 64) {
        __syncthreads();
#pragma unroll
        for (int it = 0; it < 4; ++it) {
            int R = wave * 32 + it * 8;
            llds16(Xb + (size_t)(m0 + R + srow) * 768 + k0 + sgcol, &As[R * 64]);
            llds16(Wb + (size_t)(n0 + R + srow) * 768 + k0 + sgcol, &Bs[R * 64]);
        }
        __syncthreads();
#pragma unroll
        for (int ks = 0; ks < 2; ++ks) {
            const int pg = ((ks * 4 + quad) ^ (l16 & 7)) << 3;  // physical group offset
            bf16x8 a[4], b[4];
#pragma unroll
            for (int i = 0; i < 4; ++i)
                a[i] = *(const bf16x8*)&As[(wr * 64 + i * 16 + l16) * 64 + pg];
#pragma unroll
            for (int i = 0; i < 4; ++i)
                b[i] = *(const bf16x8*)&Bs[(wc * 64 + i * 16 + l16) * 64 + pg];
#pragma unroll
            for (int i = 0; i < 4; ++i)
#pragma unroll
                for (int j = 0; j < 4; ++j)
                    acc[i][j] = __builtin_amdgcn_mfma_f32_16x16x32_bf16(a[i], b[j], acc[i][j], 0, 0, 0);
        }
    }

    const int which = n0 / 768;                       // uniform per block
    const float* bias = which == 0 ? bq : (which == 1 ? bk : bv);
#pragma unroll
    for (int i = 0; i < 4; ++i) {
        int mrow = m0 + wr * 64 + i * 16 + quad * 4;
#pragma unroll
        for (int j = 0; j < 4; ++j) {
            int n = n0 + wc * 64 + j * 16 + l16;
            int hcol = n - which * 768;
            int h = hcol >> 6, d = hcol & 63;
#pragma unroll
            for (int r = 0; r < 4; ++r) {
                int mm = mrow + r;
                int bidx = mm >> 12, s = mm & 4095;
                float y = (acc[i][j][r] + bias[hcol]) * mask[(bidx << 12) + s];
                bf16 v = (bf16)y;
                size_t mb = (size_t)(bidx * 12 + h);
                if (which == 0)      Qb[((mb << 12) + s) * 64 + d] = v;
                else if (which == 1) Kb[((mb << 12) + s) * 64 + d] = v;
                else                 Vt[((mb * 128 + (s >> 5)) * 64 + d) * 32 + (s & 31)] = v;
            }
        }
    }
}

// ---------------- exact f32 low-res projections: Qh/Kh/Vh ----------------
// Qh[mb][nb][d] = (Xh_sum[b][nb] @ W^T + tc*b) / (tc + 1e-6)
__global__ __launch_bounds__(256)
void k_lowres(const float* __restrict__ Xh, const float* __restrict__ tc,
              const float* __restrict__ Wq, const float* __restrict__ Wk,
              const float* __restrict__ Wv, const float* __restrict__ bq,
              const float* __restrict__ bk, const float* __restrict__ bv,
              float* __restrict__ Qh, float* __restrict__ Kh, float* __restrict__ Vh) {
    int nb9 = blockIdx.x, rc = blockIdx.y, t = threadIdx.x;   // grid (9, 32)
    __shared__ float xsh[8 * 768];
    for (int idx = t; idx < 8 * 768; idx += 256)
        xsh[idx] = Xh[(size_t)(rc * 8) * 768 + idx];
    __syncthreads();
    int which = nb9 / 3;
    int wcol = (nb9 % 3) * 256 + t;
    const float* W = (which == 0 ? Wq : (which == 1 ? Wk : Wv)) + (size_t)wcol * 768;
    const float* bias = which == 0 ? bq : (which == 1 ? bk : bv);
    float acc[8] = {};
    for (int k = 0; k < 768; k += 4) {
        float4 w4 = *(const float4*)(W + k);
#pragma unroll
        for (int j = 0; j < 8; ++j) {
            float4 x4 = *(const float4*)&xsh[j * 768 + k];
            acc[j] += w4.x * x4.x + w4.y * x4.y + w4.z * x4.z + w4.w * x4.w;
        }
    }
    int h = wcol >> 6, d = wcol & 63;
    float bval = bias[wcol];
    float* dst = which == 0 ? Qh : (which == 1 ? Kh : Vh);
#pragma unroll
    for (int j = 0; j < 8; ++j) {
        int row = rc * 8 + j;
        int b = row >> 7, nbr = row & 127;
        float tcv = tc[row];
        float val = (acc[j] + tcv * bval) / (tcv + 1e-6f);
        dst[(((size_t)(b * 12 + h)) * 128 + nbr) * 64 + d] = val;
    }
}

// ---------------- low-res logits + row max (f32 exact) ----------------
__global__ __launch_bounds__(256)
void k_lowlogit(const float* __restrict__ Qh, const float* __restrict__ Kh,
                float* __restrict__ prior, float* __restrict__ rowmax) {
    int mb = blockIdx.x, rc = blockIdx.y;             // grid (24, 8)
    int tid = threadIdx.x;
    __shared__ float Ksh[64 * 132];                   // [k][c] padded (528B rows, 16B aligned)
    __shared__ float Qsh[16 * 64];
    for (int idx = tid; idx < 128 * 64; idx += 256) {
        int c = idx >> 6, k = idx & 63;
        Ksh[k * 132 + c] = Kh[((size_t)mb * 128 + c) * 64 + k];
    }
    for (int idx = tid; idx < 16 * 64; idx += 256) {
        int r = idx >> 6, k = idx & 63;
        Qsh[idx] = Qh[((size_t)mb * 128 + rc * 16 + r) * 64 + k];
    }
    __syncthreads();
    int rloc = tid >> 4, cg = tid & 15;
    float acc[8] = {};
    for (int k = 0; k < 64; ++k) {
        float qv = Qsh[rloc * 64 + k];
        const float* kr = &Ksh[k * 132 + cg * 8];
#pragma unroll
        for (int j = 0; j < 8; ++j) acc[j] += qv * kr[j];
    }
    float pm = -3.4e38f;
#pragma unroll
    for (int j = 0; j < 8; ++j) { acc[j] *= 0.125f; pm = fmaxf(pm, acc[j]); }
#pragma unroll
    for (int d = 1; d < 16; d <<= 1) pm = fmaxf(pm, __shfl_xor(pm, d, 64));
    int r = rc * 16 + rloc;
    if (cg == 0) rowmax[mb * 128 + r] = pm;
    float* dst = prior + ((size_t)mb * 128 + r) * 128 + cg * 8;
#pragma unroll
    for (int j = 0; j < 8; ++j) dst[j] = acc[j] - pm;
}

// ---------------- exact top-1024 threshold + list build ----------------
// 2-bit-per-level MSB radix descent (16 levels). Keys in registers.
// Per level: per-thread VALU counts -> wave shfl_xor reduce -> lane0 atomicAdd
// into that level's preallocated LDS slots -> one barrier -> every thread
// redundantly replays the (prefix, k) decision from the shared counts.
__global__ __launch_bounds__(1024)
void k_select(const float* __restrict__ prior, unsigned char* __restrict__ selmask,
              unsigned short* __restrict__ lists, int* __restrict__ counts) {
    const int mb = blockIdx.x, tid = threadIdx.x;
    const int ln = tid & 63;
    __shared__ int lc[16 * 3];                 // [level][field 3,2,1] counts
    __shared__ int cnt[128];
    if (tid < 48) lc[tid] = 0;
    if (tid < 128) cnt[tid] = 0;

    // each thread owns 16 consecutive elements of one row: flat idx = tid*16 + j
    const int r = tid >> 3;                    // row (q-block) index, 8 threads/row
    const int cbase = (tid & 7) << 4;          // starting column
    uint key[16];
    const float4* P4 = (const float4*)(prior + (size_t)mb * 16384) + (tid << 2);
#pragma unroll
    for (int j4 = 0; j4 < 4; ++j4) {
        float4 v = P4[j4];
        float vv[4] = {v.x, v.y, v.z, v.w};
#pragma unroll
        for (int e = 0; e < 4; ++e) {
            int c = cbase + (j4 << 2) + e;
            float f = vv[e] + ((r - c <= 1 && c - r <= 1) ? 5e3f : 0.f);
            key[(j4 << 2) + e] = sortable(f);
        }
    }
    __syncthreads();                           // lc/cnt zeroed before use

    uint pfx = 0u;                             // redundant per-thread state
    int k = 1024;
#pragma unroll
    for (int lvl = 0; lvl < 16; ++lvl) {
        const int sh = 30 - 2 * lvl;
        const uint maskA = (lvl == 0) ? 0u : (0xFFFFFFFFu << (sh + 2));
        int c3 = 0, c2 = 0, c1 = 0;
#pragma unroll
        for (int j = 0; j < 16; ++j) {
            uint x = key[j];
            bool m = ((x ^ pfx) & maskA) == 0u;
            uint f = (x >> sh) & 3u;
            c3 += (m && f == 3u);
            c2 += (m && f == 2u);
            c1 += (m && f == 1u);
        }
#pragma unroll
        for (int d = 1; d < 64; d <<= 1) {
            c3 += __shfl_xor(c3, d, 64);
            c2 += __shfl_xor(c2, d, 64);
            c1 += __shfl_xor(c1, d, 64);
        }
        if (ln == 0) {
            atomicAdd(&lc[lvl * 3 + 0], c3);
            atomicAdd(&lc[lvl * 3 + 1], c2);
            atomicAdd(&lc[lvl * 3 + 2], c1);
        }
        __syncthreads();
        const int C3 = lc[lvl * 3 + 0], C2 = lc[lvl * 3 + 1], C1 = lc[lvl * 3 + 2];
        uint choose;
        if (C3 >= k)                { choose = 3u; }
        else if (C3 + C2 >= k)      { choose = 2u; k -= C3; }
        else if (C3 + C2 + C1 >= k) { choose = 1u; k -= C3 + C2; }
        else                        { choose = 0u; k -= C3 + C2 + C1; }
        pfx |= choose << sh;
    }
    const uint T = pfx;                        // exact bit pattern of 1024th-largest prior

    uint packed[4] = {0u, 0u, 0u, 0u};
#pragma unroll
    for (int j = 0; j < 16; ++j) {
        if (key[j] >= T) {
            packed[j >> 2] |= 1u << ((j & 3) << 3);
            int pos = atomicAdd(&cnt[r], 1);
            lists[((size_t)mb * 128 + r) * 128 + pos] = (unsigned short)(cbase + j);
        }
    }
    uint4 pk;
    pk.x = packed[0]; pk.y = packed[1]; pk.z = packed[2]; pk.w = packed[3];
    *(uint4*)(selmask + (size_t)mb * 16384 + (size_t)tid * 16) = pk;
    __syncthreads();
    if (tid < 128) counts[mb * 128 + tid] = cnt[tid];
}

// ---------------- high-res sparse attention: one wave per (mb, q-block) ----------------
// R3: software-prefetch next selected block's K/V fragments ahead of the
// current block's softmax chain (independent loads hide K-load latency).
__global__ __launch_bounds__(64)
void k_high(const bf16* __restrict__ Qb, const bf16* __restrict__ Kb,
            const bf16* __restrict__ Vt, const int* __restrict__ counts,
            const unsigned short* __restrict__ lists,
            float* __restrict__ high_out, float* __restrict__ high_norm,
            float* __restrict__ max_vals) {
    const int q = blockIdx.x & 127, mb = blockIdx.x >> 7;
    const int lane = threadIdx.x, quad = lane >> 4, l16 = lane & 15;
    __shared__ bf16 Pb[32 * 40];                       // stride 40 keeps 16B alignment, breaks conflicts

    const bf16* Qbase = Qb + ((size_t)mb * 4096 + q * 32) * 64;
    bf16x8 qf[2][2];
#pragma unroll
    for (int mt = 0; mt < 2; ++mt)
#pragma unroll
        for (int ks = 0; ks < 2; ++ks)
            qf[mt][ks] = *(const bf16x8*)(Qbase + (mt * 16 + l16) * 64 + ks * 32 + quad * 8);

    float m_st[2][4], l_st[2][4];
    f32x4 o[2][4] = {};
#pragma unroll
    for (int mt = 0; mt < 2; ++mt)
#pragma unroll
        for (int r = 0; r < 4; ++r) { m_st[mt][r] = -1e30f; l_st[mt][r] = 0.f; }

    int cntv = counts[mb * 128 + q];
    if (cntv > 128) cntv = 128;
    if (cntv < 1) cntv = 1;                            // diag band guarantees >=1
    const unsigned short* lst = lists + ((size_t)mb * 128 + q) * 128;

    const bf16* KB = Kb + (size_t)mb * 4096 * 64;
    const bf16* VB = Vt + (size_t)mb * 128 * 2048;

    int c0 = lst[0];
    bf16x8 kf_n[2][2], vf_n[4];
#pragma unroll
    for (int nt = 0; nt < 2; ++nt)
#pragma unroll
        for (int ks = 0; ks < 2; ++ks)
            kf_n[nt][ks] = *(const bf16x8*)(KB + ((size_t)c0 * 32 + nt * 16 + l16) * 64 + ks * 32 + quad * 8);
#pragma unroll
    for (int nd = 0; nd < 4; ++nd)
        vf_n[nd] = *(const bf16x8*)(VB + (size_t)c0 * 2048 + (nd * 16 + l16) * 32 + quad * 8);

    for (int i = 0; i < cntv; ++i) {
        bf16x8 kf[2][2], vf[4];
#pragma unroll
        for (int nt = 0; nt < 2; ++nt)
#pragma unroll
            for (int ks = 0; ks < 2; ++ks) kf[nt][ks] = kf_n[nt][ks];
#pragma unroll
        for (int nd = 0; nd < 4; ++nd) vf[nd] = vf_n[nd];

        if (i + 1 < cntv) {                            // prefetch next block
            const int cn = lst[i + 1];
#pragma unroll
            for (int nt = 0; nt < 2; ++nt)
#pragma unroll
                for (int ks = 0; ks < 2; ++ks)
                    kf_n[nt][ks] = *(const bf16x8*)(KB + ((size_t)cn * 32 + nt * 16 + l16) * 64 + ks * 32 + quad * 8);
#pragma unroll
            for (int nd = 0; nd < 4; ++nd)
                vf_n[nd] = *(const bf16x8*)(VB + (size_t)cn * 2048 + (nd * 16 + l16) * 32 + quad * 8);
        }

        f32x4 sf[2][2] = {};
#pragma unroll
        for (int mt = 0; mt < 2; ++mt)
#pragma unroll
            for (int nt = 0; nt < 2; ++nt) {
                sf[mt][nt] = __builtin_amdgcn_mfma_f32_16x16x32_bf16(qf[mt][0], kf[nt][0], sf[mt][nt], 0, 0, 0);
                sf[mt][nt] = __builtin_amdgcn_mfma_f32_16x16x32_bf16(qf[mt][1], kf[nt][1], sf[mt][nt], 0, 0, 0);
                sf[mt][nt] *= 0.125f;
            }

        float rmx[2][4];
#pragma unroll
        for (int mt = 0; mt < 2; ++mt)
#pragma unroll
            for (int r = 0; r < 4; ++r)
                rmx[mt][r] = fmaxf(sf[mt][0][r], sf[mt][1][r]);
#pragma unroll
        for (int d = 1; d < 16; d <<= 1)
#pragma unroll
            for (int mt = 0; mt < 2; ++mt)
#pragma unroll
                for (int r = 0; r < 4; ++r)
                    rmx[mt][r] = fmaxf(rmx[mt][r], __shfl_xor(rmx[mt][r], d, 64));

        float alpha[2][4], rs[2][4];
#pragma unroll
        for (int mt = 0; mt < 2; ++mt)
#pragma unroll
            for (int r = 0; r < 4; ++r) {
                float mn = fmaxf(m_st[mt][r], rmx[mt][r]);
                alpha[mt][r] = __expf(m_st[mt][r] - mn);
                m_st[mt][r] = mn;
                rs[mt][r] = 0.f;
            }
#pragma unroll
        for (int mt = 0; mt < 2; ++mt)
#pragma unroll
            for (int nt = 0; nt < 2; ++nt)
#pragma unroll
                for (int r = 0; r < 4; ++r) {
                    float p = __expf(sf[mt][nt][r] - m_st[mt][r]);
                    rs[mt][r] += p;
                    Pb[(mt * 16 + quad * 4 + r) * 40 + nt * 16 + l16] = (bf16)p;
                }
#pragma unroll
        for (int d = 1; d < 16; d <<= 1)
#pragma unroll
            for (int mt = 0; mt < 2; ++mt)
#pragma unroll
                for (int r = 0; r < 4; ++r)
                    rs[mt][r] += __shfl_xor(rs[mt][r], d, 64);
#pragma unroll
        for (int mt = 0; mt < 2; ++mt)
#pragma unroll
            for (int r = 0; r < 4; ++r)
                l_st[mt][r] = l_st[mt][r] * alpha[mt][r] + rs[mt][r];
#pragma unroll
        for (int mt = 0; mt < 2; ++mt)
#pragma unroll
            for (int nd = 0; nd < 4; ++nd)
#pragma unroll
                for (int r = 0; r < 4; ++r)
                    o[mt][nd][r] *= alpha[mt][r];

        __syncthreads();                               // Pb writes -> A-frag reads (1 wave)
        bf16x8 pf[2];
#pragma unroll
        for (int mt = 0; mt < 2; ++mt)
            pf[mt] = *(const bf16x8*)&Pb[(mt * 16 + l16) * 40 + quad * 8];
#pragma unroll
        for (int mt = 0; mt < 2; ++mt)
#pragma unroll
            for (int nd = 0; nd < 4; ++nd)
                o[mt][nd] = __builtin_amdgcn_mfma_f32_16x16x32_bf16(pf[mt], vf[nd], o[mt][nd], 0, 0, 0);
        __syncthreads();
    }

    float* HO = high_out + ((size_t)mb * 4096 + q * 32) * 64;
#pragma unroll
    for (int mt = 0; mt < 2; ++mt)
#pragma unroll
        for (int nd = 0; nd < 4; ++nd)
#pragma unroll
            for (int r = 0; r < 4; ++r)
                HO[(mt * 16 + quad * 4 + r) * 64 + nd * 16 + l16] = o[mt][nd][r];
    if (l16 == 0) {
#pragma unroll
        for (int mt = 0; mt < 2; ++mt)
#pragma unroll
            for (int r = 0; r < 4; ++r) {
                int row = q * 32 + mt * 16 + quad * 4 + r;
                high_norm[(size_t)mb * 4096 + row] = l_st[mt][r];
                max_vals[(size_t)mb * 4096 + row] = fmaxf(m_st[mt][r], -1e6f);
            }
    }
}

// ---------------- low-res attention over non-selected blocks ----------------
__global__ __launch_bounds__(64)
void k_lowout(const float* __restrict__ prior, const unsigned char* __restrict__ selmask,
              const float* __restrict__ tc, const float* __restrict__ Vh,
              float* __restrict__ low_out, float* __restrict__ low_norm) {
    const int q = blockIdx.x & 127, mb = blockIdx.x >> 7;
    const int d = threadIdx.x;
    const float* pn = prior + ((size_t)mb * 128 + q) * 128;
    const uint4* smv = (const uint4*)(selmask + ((size_t)mb * 128 + q) * 128);
    uint sm32[32];
#pragma unroll
    for (int w = 0; w < 8; ++w) {
        uint4 u = smv[w];
        sm32[w * 4 + 0] = u.x; sm32[w * 4 + 1] = u.y;
        sm32[w * 4 + 2] = u.z; sm32[w * 4 + 3] = u.w;
    }
    const float* tcb = tc + (mb / 12) * 128;
    const float* Vb = Vh + (size_t)mb * 128 * 64;
    float acc = 0.f, nrm = 0.f;
#pragma unroll 4
    for (int c = 0; c < 128; ++c) {
        if (!((sm32[c >> 2] >> ((c & 3) << 3)) & 1u)) {
            float w = __expf(pn[c]) * tcb[c];
            acc += w * Vb[c * 64 + d];
            nrm += w;
        }
    }
    low_out[((size_t)mb * 128 + q) * 64 + d] = acc;
    if (d == 0) low_norm[mb * 128 + q] = nrm;
}

// ---------------- final combine ----------------
__global__ __launch_bounds__(256)
void k_combine(const float* __restrict__ high_out, const float* __restrict__ high_norm,
               const float* __restrict__ max_vals, const float* __restrict__ low_out,
               const float* __restrict__ low_norm, const float* __restrict__ rowmax,
               const float* __restrict__ mask, float* __restrict__ out) {
    int gid = blockIdx.x * 256 + threadIdx.x;          // over 24*4096*64
    if (gid >= 6291456) return;
    int d = gid & 63;
    int s = (gid >> 6) & 4095;
    int mb = gid >> 18;
    int b = mb / 12, h = mb - b * 12;
    int q = s >> 5;
    float ho = high_out[gid];
    float hn = high_norm[(mb << 12) + s];
    float mv = max_vals[(mb << 12) + s];
    float rm = rowmax[mb * 128 + q];
    float lo = low_out[((size_t)mb * 128 + q) * 64 + d];
    float ln = low_norm[mb * 128 + q];
    float mk = mask[(b << 12) + s];
    float lcr = (rm - mv) * mk;
    float lcf = __expf(fminf(lcr, 0.f));
    float hcf = __expf(-fmaxf(lcr, 0.f));
    float val = (ho * hcf + lo * lcf) / (hn * hcf + ln * lcf + 1e-6f);
    out[((size_t)(b * 4096 + s)) * 768 + h * 64 + d] = val;
}

extern "C" void kernel_launch(void* const* d_in, const int* in_sizes, int n_in,
                              void* d_out, int out_size, void* d_ws, size_t ws_size,
                              hipStream_t stream) {
    (void)in_sizes; (void)n_in; (void)out_size; (void)ws_size;
    const float* X    = (const float*)d_in[0];
    const float* mask = (const float*)d_in[1];
    const float* Wq   = (const float*)d_in[2];
    const float* bq   = (const float*)d_in[3];
    const float* Wk   = (const float*)d_in[4];
    const float* bk   = (const float*)d_in[5];
    const float* Wv   = (const float*)d_in[6];
    const float* bv   = (const float*)d_in[7];
    float* out = (float*)d_out;

    char* ws = (char*)d_ws;
    size_t off = 0;
    auto alloc = [&](size_t bytes) -> void* {
        off = (off + 255) & ~(size_t)255;
        void* p = ws + off;
        off += bytes;
        return p;
    };
    bf16* Xb  = (bf16*)alloc((size_t)8192 * 768 * 2);
    bf16* Wb  = (bf16*)alloc((size_t)2304 * 768 * 2);
    bf16* Qb  = (bf16*)alloc((size_t)24 * 4096 * 64 * 2);
    bf16* Kb  = (bf16*)alloc((size_t)24 * 4096 * 64 * 2);
    bf16* Vt  = (bf16*)alloc((size_t)24 * 4096 * 64 * 2);
    float* Xh = (float*)alloc((size_t)256 * 768 * 4);
    float* tc = (float*)alloc(256 * 4);
    float* Qh = (float*)alloc((size_t)24 * 128 * 64 * 4);
    float* Kh = (float*)alloc((size_t)24 * 128 * 64 * 4);
    float* Vh = (float*)alloc((size_t)24 * 128 * 64 * 4);
    float* prior = (float*)alloc((size_t)24 * 16384 * 4);
    float* rowmax = (float*)alloc(24 * 128 * 4);
    unsigned char* selmask = (unsigned char*)alloc((size_t)24 * 16384);
    unsigned short* lists = (unsigned short*)alloc((size_t)24 * 128 * 128 * 2);
    int* counts = (int*)alloc(24 * 128 * 4);
    float* high_out  = (float*)alloc((size_t)24 * 4096 * 64 * 4);
    float* high_norm = (float*)alloc((size_t)24 * 4096 * 4);
    float* max_vals  = (float*)alloc((size_t)24 * 4096 * 4);
    float* low_out   = (float*)alloc((size_t)24 * 128 * 64 * 4);
    float* low_norm  = (float*)alloc(24 * 128 * 4);

    k_prep<<<256, 192, 0, stream>>>(X, mask, Xb, Xh, tc);
    k_convW<<<1728, 256, 0, stream>>>(Wq, Wk, Wv, Wb);
    k_gemm_qkv<<<dim3(64, 18), 256, 0, stream>>>(Xb, Wb, bq, bk, bv, mask, Qb, Kb, Vt);
    k_lowres<<<dim3(9, 32), 256, 0, stream>>>(Xh, tc, Wq, Wk, Wv, bq, bk, bv, Qh, Kh, Vh);
    k_lowlogit<<<dim3(24, 8), 256, 0, stream>>>(Qh, Kh, prior, rowmax);
    k_select<<<24, 1024, 0, stream>>>(prior, selmask, lists, counts);
    k_high<<<3072, 64, 0, stream>>>(Qb, Kb, Vt, counts, lists, high_out, high_norm, max_vals);
    k_lowout<<<3072, 64, 0, stream>>>(prior, selmask, tc, Vh, low_out, low_norm);
    k_combine<<<24576, 256, 0, stream>>>(high_out, high_norm, max_vals, low_out, low_norm,
                                         rowmax, mask, out);
}

// Round 5
// 343.032 us; speedup vs baseline: 1.2844x; 1.0376x over previous
//
#include <hip/hip_runtime.h>

typedef __bf16 bf16;
typedef float f32x4 __attribute__((ext_vector_type(4)));
typedef bf16 bf16x8 __attribute__((ext_vector_type(8)));
typedef bf16 bf16x4 __attribute__((ext_vector_type(4)));
typedef unsigned int uint;

// Problem constants: B=2 S=4096 D=768 H=12 HD=64 BLK=32 NBR=128 MB=24 NUM_BLOCK=1024 DIAG_N=3

__device__ __forceinline__ void llds16(const bf16* g, bf16* l) {
    __builtin_amdgcn_global_load_lds((const __attribute__((address_space(1))) uint*)g,
                                     (__attribute__((address_space(3))) uint*)l, 16, 0, 0);
}

__device__ __forceinline__ uint sortable(float f) {
    uint u = __float_as_uint(f);
    return u ^ (uint)(((int)u >> 31) | 0x80000000);
}

// ---------------- fused prep: X->bf16 conversion + masked block sums + token counts ----
__global__ __launch_bounds__(192)
void k_prep(const float* __restrict__ X, const float* __restrict__ mask,
            bf16* __restrict__ Xb, float* __restrict__ Xh, float* __restrict__ tc) {
    const int row = blockIdx.x;                 // b*128 + nbr
    const int b = row >> 7, nbr = row & 127;
    const int t = threadIdx.x;                  // float4 column 0..191
    const float4* xp = (const float4*)(X + (size_t)(b * 4096 + nbr * 32) * 768) + t;
    bf16x4* xbp = (bf16x4*)(Xb + (size_t)(b * 4096 + nbr * 32) * 768) + t;
    const float* mp = mask + b * 4096 + nbr * 32;
    float4 s = {0.f, 0.f, 0.f, 0.f};
    float tcs = 0.f;
#pragma unroll 4
    for (int tok = 0; tok < 32; ++tok) {
        float4 v = xp[(size_t)tok * 192];
        float m = mp[tok];
        s.x += v.x * m; s.y += v.y * m; s.z += v.z * m; s.w += v.w * m;
        tcs += m;
        bf16x4 o = {(bf16)v.x, (bf16)v.y, (bf16)v.z, (bf16)v.w};
        xbp[(size_t)tok * 192] = o;
    }
    ((float4*)(Xh + (size_t)row * 768))[t] = s;
    if (t == 0) tc[row] = tcs;
}

__global__ void k_convW(const float* __restrict__ Wq, const float* __restrict__ Wk,
                        const float* __restrict__ Wv, bf16* __restrict__ Wb) {
    int i = blockIdx.x * 256 + threadIdx.x;          // over 2304*768/4
    if (i >= 442368) return;
    int n = (i << 2) / 768;
    int k = (i << 2) % 768;
    const float* W = n < 768 ? Wq : (n < 1536 ? Wk : Wv);
    int nn = n - (n < 768 ? 0 : (n < 1536 ? 768 : 1536));
    float4 f = *(const float4*)(W + (size_t)nn * 768 + k);
    bf16x4 o = {(bf16)f.x, (bf16)f.y, (bf16)f.z, (bf16)f.w};
    ((bf16x4*)Wb)[i] = o;
}

// ---------------- QKV projection GEMM (bf16 MFMA, 256x128 tile, BK=64, XOR swizzle) ----
// R4: M-tile 256 (wave tile 128x64, acc 8x4). Per ks-step: 12 ds_read_b128 vs 64
// MFMA -> MFMA-bound at wave level (was 8 reads / 16 MFMA = LDS-bound at 128 tile).
// Swizzle identical to R3 (verified): logical (row,g) at physical g^(row&7).
__global__ __launch_bounds__(256, 2)
void k_gemm_qkv(const bf16* __restrict__ Xb, const bf16* __restrict__ Wb,
                const float* __restrict__ bq, const float* __restrict__ bk,
                const float* __restrict__ bv, const float* __restrict__ mask,
                bf16* __restrict__ Qb, bf16* __restrict__ Kb, bf16* __restrict__ Vt) {
    __shared__ bf16 As[256 * 64];
    __shared__ bf16 Bs[128 * 64];
    const int tid = threadIdx.x;
    const int wave = tid >> 6, lane = tid & 63;
    const int quad = lane >> 4, l16 = lane & 15;
    const int wr = wave >> 1, wc = wave & 1;
    const int m0 = blockIdx.x * 256, n0 = blockIdx.y * 128;
    const int srow = lane >> 3;                              // row within 8-row chunk
    const int sgcol = (((lane & 7) ^ (srow & 7)) << 3);      // swizzled source col

    f32x4 acc[8][4] = {};

    for (int k0 = 0; k0 < 768; k0 += 64) {
        __syncthreads();
#pragma unroll
        for (int it = 0; it < 8; ++it) {                     // As: 256 rows, 8/call
            int R = wave * 64 + it * 8;
            llds16(Xb + (size_t)(m0 + R + srow) * 768 + k0 + sgcol, &As[R * 64]);
        }
#pragma unroll
        for (int it = 0; it < 4; ++it) {                     // Bs: 128 rows
            int R = wave * 32 + it * 8;
            llds16(Wb + (size_t)(n0 + R + srow) * 768 + k0 + sgcol, &Bs[R * 64]);
        }
        __syncthreads();
#pragma unroll
        for (int ks = 0; ks < 2; ++ks) {
            const int pg = ((ks * 4 + quad) ^ (l16 & 7)) << 3;  // physical group offset
            bf16x8 a[8], b[4];
#pragma unroll
            for (int i = 0; i < 8; ++i)
                a[i] = *(const bf16x8*)&As[(wr * 128 + i * 16 + l16) * 64 + pg];
#pragma unroll
            for (int j = 0; j < 4; ++j)
                b[j] = *(const bf16x8*)&Bs[(wc * 64 + j * 16 + l16) * 64 + pg];
#pragma unroll
            for (int i = 0; i < 8; ++i)
#pragma unroll
                for (int j = 0; j < 4; ++j)
                    acc[i][j] = __builtin_amdgcn_mfma_f32_16x16x32_bf16(a[i], b[j], acc[i][j], 0, 0, 0);
        }
    }

    const int which = n0 / 768;                       // uniform per block (768%128==0)
    const float* bias = which == 0 ? bq : (which == 1 ? bk : bv);
#pragma unroll
    for (int i = 0; i < 8; ++i) {
        int mrow = m0 + wr * 128 + i * 16 + quad * 4;
#pragma unroll
        for (int j = 0; j < 4; ++j) {
            int n = n0 + wc * 64 + j * 16 + l16;
            int hcol = n - which * 768;
            int h = hcol >> 6, d = hcol & 63;
#pragma unroll
            for (int r = 0; r < 4; ++r) {
                int mm = mrow + r;
                int bidx = mm >> 12, s = mm & 4095;
                float y = (acc[i][j][r] + bias[hcol]) * mask[(bidx << 12) + s];
                bf16 v = (bf16)y;
                size_t mb = (size_t)(bidx * 12 + h);
                if (which == 0)      Qb[((mb << 12) + s) * 64 + d] = v;
                else if (which == 1) Kb[((mb << 12) + s) * 64 + d] = v;
                else                 Vt[((mb * 128 + (s >> 5)) * 64 + d) * 32 + (s & 31)] = v;
            }
        }
    }
}

// ---------------- exact f32 low-res projections: Qh/Kh/Vh ----------------
__global__ __launch_bounds__(256)
void k_lowres(const float* __restrict__ Xh, const float* __restrict__ tc,
              const float* __restrict__ Wq, const float* __restrict__ Wk,
              const float* __restrict__ Wv, const float* __restrict__ bq,
              const float* __restrict__ bk, const float* __restrict__ bv,
              float* __restrict__ Qh, float* __restrict__ Kh, float* __restrict__ Vh) {
    int nb9 = blockIdx.x, rc = blockIdx.y, t = threadIdx.x;   // grid (9, 32)
    __shared__ float xsh[8 * 768];
    for (int idx = t; idx < 8 * 768; idx += 256)
        xsh[idx] = Xh[(size_t)(rc * 8) * 768 + idx];
    __syncthreads();
    int which = nb9 / 3;
    int wcol = (nb9 % 3) * 256 + t;
    const float* W = (which == 0 ? Wq : (which == 1 ? Wk : Wv)) + (size_t)wcol * 768;
    const float* bias = which == 0 ? bq : (which == 1 ? bk : bv);
    float acc[8] = {};
    for (int k = 0; k < 768; k += 4) {
        float4 w4 = *(const float4*)(W + k);
#pragma unroll
        for (int j = 0; j < 8; ++j) {
            float4 x4 = *(const float4*)&xsh[j * 768 + k];
            acc[j] += w4.x * x4.x + w4.y * x4.y + w4.z * x4.z + w4.w * x4.w;
        }
    }
    int h = wcol >> 6, d = wcol & 63;
    float bval = bias[wcol];
    float* dst = which == 0 ? Qh : (which == 1 ? Kh : Vh);
#pragma unroll
    for (int j = 0; j < 8; ++j) {
        int row = rc * 8 + j;
        int b = row >> 7, nbr = row & 127;
        float tcv = tc[row];
        float val = (acc[j] + tcv * bval) / (tcv + 1e-6f);
        dst[(((size_t)(b * 12 + h)) * 128 + nbr) * 64 + d] = val;
    }
}

// ---------------- low-res logits + row max (f32 exact) ----------------
__global__ __launch_bounds__(256)
void k_lowlogit(const float* __restrict__ Qh, const float* __restrict__ Kh,
                float* __restrict__ prior, float* __restrict__ rowmax) {
    int mb = blockIdx.x, rc = blockIdx.y;             // grid (24, 8)
    int tid = threadIdx.x;
    __shared__ float Ksh[64 * 132];                   // [k][c] padded
    __shared__ float Qsh[16 * 64];
    for (int idx = tid; idx < 128 * 64; idx += 256) {
        int c = idx >> 6, k = idx & 63;
        Ksh[k * 132 + c] = Kh[((size_t)mb * 128 + c) * 64 + k];
    }
    for (int idx = tid; idx < 16 * 64; idx += 256) {
        int r = idx >> 6, k = idx & 63;
        Qsh[idx] = Qh[((size_t)mb * 128 + rc * 16 + r) * 64 + k];
    }
    __syncthreads();
    int rloc = tid >> 4, cg = tid & 15;
    float acc[8] = {};
    for (int k = 0; k < 64; ++k) {
        float qv = Qsh[rloc * 64 + k];
        const float* kr = &Ksh[k * 132 + cg * 8];
#pragma unroll
        for (int j = 0; j < 8; ++j) acc[j] += qv * kr[j];
    }
    float pm = -3.4e38f;
#pragma unroll
    for (int j = 0; j < 8; ++j) { acc[j] *= 0.125f; pm = fmaxf(pm, acc[j]); }
#pragma unroll
    for (int d = 1; d < 16; d <<= 1) pm = fmaxf(pm, __shfl_xor(pm, d, 64));
    int r = rc * 16 + rloc;
    if (cg == 0) rowmax[mb * 128 + r] = pm;
    float* dst = prior + ((size_t)mb * 128 + r) * 128 + cg * 8;
#pragma unroll
    for (int j = 0; j < 8; ++j) dst[j] = acc[j] - pm;
}

// ---------------- exact top-1024 threshold + list build (2-bit radix descent) --------
__global__ __launch_bounds__(1024)
void k_select(const float* __restrict__ prior, unsigned char* __restrict__ selmask,
              unsigned short* __restrict__ lists, int* __restrict__ counts) {
    const int mb = blockIdx.x, tid = threadIdx.x;
    const int ln = tid & 63;
    __shared__ int lc[16 * 3];                 // [level][field 3,2,1] counts
    __shared__ int cnt[128];
    if (tid < 48) lc[tid] = 0;
    if (tid < 128) cnt[tid] = 0;

    const int r = tid >> 3;                    // row (q-block) index, 8 threads/row
    const int cbase = (tid & 7) << 4;          // starting column
    uint key[16];
    const float4* P4 = (const float4*)(prior + (size_t)mb * 16384) + (tid << 2);
#pragma unroll
    for (int j4 = 0; j4 < 4; ++j4) {
        float4 v = P4[j4];
        float vv[4] = {v.x, v.y, v.z, v.w};
#pragma unroll
        for (int e = 0; e < 4; ++e) {
            int c = cbase + (j4 << 2) + e;
            float f = vv[e] + ((r - c <= 1 && c - r <= 1) ? 5e3f : 0.f);
            key[(j4 << 2) + e] = sortable(f);
        }
    }
    __syncthreads();                           // lc/cnt zeroed before use

    uint pfx = 0u;
    int k = 1024;
#pragma unroll
    for (int lvl = 0; lvl < 16; ++lvl) {
        const int sh = 30 - 2 * lvl;
        const uint maskA = (lvl == 0) ? 0u : (0xFFFFFFFFu << (sh + 2));
        int c3 = 0, c2 = 0, c1 = 0;
#pragma unroll
        for (int j = 0; j < 16; ++j) {
            uint x = key[j];
            bool m = ((x ^ pfx) & maskA) == 0u;
            uint f = (x >> sh) & 3u;
            c3 += (m && f == 3u);
            c2 += (m && f == 2u);
            c1 += (m && f == 1u);
        }
#pragma unroll
        for (int d = 1; d < 64; d <<= 1) {
            c3 += __shfl_xor(c3, d, 64);
            c2 += __shfl_xor(c2, d, 64);
            c1 += __shfl_xor(c1, d, 64);
        }
        if (ln == 0) {
            atomicAdd(&lc[lvl * 3 + 0], c3);
            atomicAdd(&lc[lvl * 3 + 1], c2);
            atomicAdd(&lc[lvl * 3 + 2], c1);
        }
        __syncthreads();
        const int C3 = lc[lvl * 3 + 0], C2 = lc[lvl * 3 + 1], C1 = lc[lvl * 3 + 2];
        uint choose;
        if (C3 >= k)                { choose = 3u; }
        else if (C3 + C2 >= k)      { choose = 2u; k -= C3; }
        else if (C3 + C2 + C1 >= k) { choose = 1u; k -= C3 + C2; }
        else                        { choose = 0u; k -= C3 + C2 + C1; }
        pfx |= choose << sh;
    }
    const uint T = pfx;                        // exact bit pattern of 1024th-largest prior

    uint packed[4] = {0u, 0u, 0u, 0u};
#pragma unroll
    for (int j = 0; j < 16; ++j) {
        if (key[j] >= T) {
            packed[j >> 2] |= 1u << ((j & 3) << 3);
            int pos = atomicAdd(&cnt[r], 1);
            lists[((size_t)mb * 128 + r) * 128 + pos] = (unsigned short)(cbase + j);
        }
    }
    uint4 pk;
    pk.x = packed[0]; pk.y = packed[1]; pk.z = packed[2]; pk.w = packed[3];
    *(uint4*)(selmask + (size_t)mb * 16384 + (size_t)tid * 16) = pk;
    __syncthreads();
    if (tid < 128) counts[mb * 128 + tid] = cnt[tid];
}

// ---------------- low-res attention over non-selected blocks ----------------
__global__ __launch_bounds__(64)
void k_lowout(const float* __restrict__ prior, const unsigned char* __restrict__ selmask,
              const float* __restrict__ tc, const float* __restrict__ Vh,
              float* __restrict__ low_out, float* __restrict__ low_norm) {
    const int q = blockIdx.x & 127, mb = blockIdx.x >> 7;
    const int d = threadIdx.x;
    const float* pn = prior + ((size_t)mb * 128 + q) * 128;
    const uint4* smv = (const uint4*)(selmask + ((size_t)mb * 128 + q) * 128);
    uint sm32[32];
#pragma unroll
    for (int w = 0; w < 8; ++w) {
        uint4 u = smv[w];
        sm32[w * 4 + 0] = u.x; sm32[w * 4 + 1] = u.y;
        sm32[w * 4 + 2] = u.z; sm32[w * 4 + 3] = u.w;
    }
    const float* tcb = tc + (mb / 12) * 128;
    const float* Vb = Vh + (size_t)mb * 128 * 64;
    float acc = 0.f, nrm = 0.f;
#pragma unroll 4
    for (int c = 0; c < 128; ++c) {
        if (!((sm32[c >> 2] >> ((c & 3) << 3)) & 1u)) {
            float w = __expf(pn[c]) * tcb[c];
            acc += w * Vb[c * 64 + d];
            nrm += w;
        }
    }
    low_out[((size_t)mb * 128 + q) * 64 + d] = acc;
    if (d == 0) low_norm[mb * 128 + q] = nrm;
}

// ---------------- high-res sparse attention + fused combine epilogue ----------------
// One wave per (mb, q-block); K/V register prefetch; R4: combine folded in — reads
// rowmax/low_out/low_norm/mask and writes final `out` directly (high_out/high_norm/
// max_vals buffers and k_combine dispatch eliminated).
__global__ __launch_bounds__(64)
void k_high(const bf16* __restrict__ Qb, const bf16* __restrict__ Kb,
            const bf16* __restrict__ Vt, const int* __restrict__ counts,
            const unsigned short* __restrict__ lists,
            const float* __restrict__ rowmax, const float* __restrict__ low_out,
            const float* __restrict__ low_norm, const float* __restrict__ mask,
            float* __restrict__ out) {
    const int q = blockIdx.x & 127, mb = blockIdx.x >> 7;
    const int lane = threadIdx.x, quad = lane >> 4, l16 = lane & 15;
    __shared__ bf16 Pb[32 * 40];

    const bf16* Qbase = Qb + ((size_t)mb * 4096 + q * 32) * 64;
    bf16x8 qf[2][2];
#pragma unroll
    for (int mt = 0; mt < 2; ++mt)
#pragma unroll
        for (int ks = 0; ks < 2; ++ks)
            qf[mt][ks] = *(const bf16x8*)(Qbase + (mt * 16 + l16) * 64 + ks * 32 + quad * 8);

    float m_st[2][4], l_st[2][4];
    f32x4 o[2][4] = {};
#pragma unroll
    for (int mt = 0; mt < 2; ++mt)
#pragma unroll
        for (int r = 0; r < 4; ++r) { m_st[mt][r] = -1e30f; l_st[mt][r] = 0.f; }

    int cntv = counts[mb * 128 + q];
    if (cntv > 128) cntv = 128;
    if (cntv < 1) cntv = 1;                            // diag band guarantees >=1
    const unsigned short* lst = lists + ((size_t)mb * 128 + q) * 128;

    const bf16* KB = Kb + (size_t)mb * 4096 * 64;
    const bf16* VB = Vt + (size_t)mb * 128 * 2048;

    int c0 = lst[0];
    bf16x8 kf_n[2][2], vf_n[4];
#pragma unroll
    for (int nt = 0; nt < 2; ++nt)
#pragma unroll
        for (int ks = 0; ks < 2; ++ks)
            kf_n[nt][ks] = *(const bf16x8*)(KB + ((size_t)c0 * 32 + nt * 16 + l16) * 64 + ks * 32 + quad * 8);
#pragma unroll
    for (int nd = 0; nd < 4; ++nd)
        vf_n[nd] = *(const bf16x8*)(VB + (size_t)c0 * 2048 + (nd * 16 + l16) * 32 + quad * 8);

    for (int i = 0; i < cntv; ++i) {
        bf16x8 kf[2][2], vf[4];
#pragma unroll
        for (int nt = 0; nt < 2; ++nt)
#pragma unroll
            for (int ks = 0; ks < 2; ++ks) kf[nt][ks] = kf_n[nt][ks];
#pragma unroll
        for (int nd = 0; nd < 4; ++nd) vf[nd] = vf_n[nd];

        if (i + 1 < cntv) {                            // prefetch next block
            const int cn = lst[i + 1];
#pragma unroll
            for (int nt = 0; nt < 2; ++nt)
#pragma unroll
                for (int ks = 0; ks < 2; ++ks)
                    kf_n[nt][ks] = *(const bf16x8*)(KB + ((size_t)cn * 32 + nt * 16 + l16) * 64 + ks * 32 + quad * 8);
#pragma unroll
            for (int nd = 0; nd < 4; ++nd)
                vf_n[nd] = *(const bf16x8*)(VB + (size_t)cn * 2048 + (nd * 16 + l16) * 32 + quad * 8);
        }

        f32x4 sf[2][2] = {};
#pragma unroll
        for (int mt = 0; mt < 2; ++mt)
#pragma unroll
            for (int nt = 0; nt < 2; ++nt) {
                sf[mt][nt] = __builtin_amdgcn_mfma_f32_16x16x32_bf16(qf[mt][0], kf[nt][0], sf[mt][nt], 0, 0, 0);
                sf[mt][nt] = __builtin_amdgcn_mfma_f32_16x16x32_bf16(qf[mt][1], kf[nt][1], sf[mt][nt], 0, 0, 0);
                sf[mt][nt] *= 0.125f;
            }

        float rmx[2][4];
#pragma unroll
        for (int mt = 0; mt < 2; ++mt)
#pragma unroll
            for (int r = 0; r < 4; ++r)
                rmx[mt][r] = fmaxf(sf[mt][0][r], sf[mt][1][r]);
#pragma unroll
        for (int d = 1; d < 16; d <<= 1)
#pragma unroll
            for (int mt = 0; mt < 2; ++mt)
#pragma unroll
                for (int r = 0; r < 4; ++r)
                    rmx[mt][r] = fmaxf(rmx[mt][r], __shfl_xor(rmx[mt][r], d, 64));

        float alpha[2][4], rs[2][4];
#pragma unroll
        for (int mt = 0; mt < 2; ++mt)
#pragma unroll
            for (int r = 0; r < 4; ++r) {
                float mn = fmaxf(m_st[mt][r], rmx[mt][r]);
                alpha[mt][r] = __expf(m_st[mt][r] - mn);
                m_st[mt][r] = mn;
                rs[mt][r] = 0.f;
            }
#pragma unroll
        for (int mt = 0; mt < 2; ++mt)
#pragma unroll
            for (int nt = 0; nt < 2; ++nt)
#pragma unroll
                for (int r = 0; r < 4; ++r) {
                    float p = __expf(sf[mt][nt][r] - m_st[mt][r]);
                    rs[mt][r] += p;
                    Pb[(mt * 16 + quad * 4 + r) * 40 + nt * 16 + l16] = (bf16)p;
                }
#pragma unroll
        for (int d = 1; d < 16; d <<= 1)
#pragma unroll
            for (int mt = 0; mt < 2; ++mt)
#pragma unroll
                for (int r = 0; r < 4; ++r)
                    rs[mt][r] += __shfl_xor(rs[mt][r], d, 64);
#pragma unroll
        for (int mt = 0; mt < 2; ++mt)
#pragma unroll
            for (int r = 0; r < 4; ++r)
                l_st[mt][r] = l_st[mt][r] * alpha[mt][r] + rs[mt][r];
#pragma unroll
        for (int mt = 0; mt < 2; ++mt)
#pragma unroll
            for (int nd = 0; nd < 4; ++nd)
#pragma unroll
                for (int r = 0; r < 4; ++r)
                    o[mt][nd][r] *= alpha[mt][r];

        __syncthreads();                               // Pb writes -> A-frag reads (1 wave)
        bf16x8 pf[2];
#pragma unroll
        for (int mt = 0; mt < 2; ++mt)
            pf[mt] = *(const bf16x8*)&Pb[(mt * 16 + l16) * 40 + quad * 8];
#pragma unroll
        for (int mt = 0; mt < 2; ++mt)
#pragma unroll
            for (int nd = 0; nd < 4; ++nd)
                o[mt][nd] = __builtin_amdgcn_mfma_f32_16x16x32_bf16(pf[mt], vf[nd], o[mt][nd], 0, 0, 0);
        __syncthreads();
    }

    // ---- fused combine epilogue ----
    const int b = mb / 12, h = mb - b * 12;
    const float rm = rowmax[mb * 128 + q];
    const float ln = low_norm[mb * 128 + q];
    const float* LO = low_out + ((size_t)mb * 128 + q) * 64;
#pragma unroll
    for (int mt = 0; mt < 2; ++mt)
#pragma unroll
        for (int r = 0; r < 4; ++r) {
            const int s = q * 32 + mt * 16 + quad * 4 + r;
            const float mv = fmaxf(m_st[mt][r], -1e6f);
            const float hn = l_st[mt][r];
            const float mk = mask[(b << 12) + s];
            const float lcr = (rm - mv) * mk;
            const float lcf = __expf(fminf(lcr, 0.f));
            const float hcf = __expf(-fmaxf(lcr, 0.f));
            const float den = 1.0f / (hn * hcf + ln * lcf + 1e-6f);
            float* op = out + ((size_t)(b * 4096 + s)) * 768 + h * 64;
#pragma unroll
            for (int nd = 0; nd < 4; ++nd) {
                const int d = nd * 16 + l16;
                op[d] = (o[mt][nd][r] * hcf + LO[d] * lcf) * den;
            }
        }
}

extern "C" void kernel_launch(void* const* d_in, const int* in_sizes, int n_in,
                              void* d_out, int out_size, void* d_ws, size_t ws_size,
                              hipStream_t stream) {
    (void)in_sizes; (void)n_in; (void)out_size; (void)ws_size;
    const float* X    = (const float*)d_in[0];
    const float* mask = (const float*)d_in[1];
    const float* Wq   = (const float*)d_in[2];
    const float* bq   = (const float*)d_in[3];
    const float* Wk   = (const float*)d_in[4];
    const float* bk   = (const float*)d_in[5];
    const float* Wv   = (const float*)d_in[6];
    const float* bv   = (const float*)d_in[7];
    float* out = (float*)d_out;

    char* ws = (char*)d_ws;
    size_t off = 0;
    auto alloc = [&](size_t bytes) -> void* {
        off = (off + 255) & ~(size_t)255;
        void* p = ws + off;
        off += bytes;
        return p;
    };
    bf16* Xb  = (bf16*)alloc((size_t)8192 * 768 * 2);
    bf16* Wb  = (bf16*)alloc((size_t)2304 * 768 * 2);
    bf16* Qb  = (bf16*)alloc((size_t)24 * 4096 * 64 * 2);
    bf16* Kb  = (bf16*)alloc((size_t)24 * 4096 * 64 * 2);
    bf16* Vt  = (bf16*)alloc((size_t)24 * 4096 * 64 * 2);
    float* Xh = (float*)alloc((size_t)256 * 768 * 4);
    float* tc = (float*)alloc(256 * 4);
    float* Qh = (float*)alloc((size_t)24 * 128 * 64 * 4);
    float* Kh = (float*)alloc((size_t)24 * 128 * 64 * 4);
    float* Vh = (float*)alloc((size_t)24 * 128 * 64 * 4);
    float* prior = (float*)alloc((size_t)24 * 16384 * 4);
    float* rowmax = (float*)alloc(24 * 128 * 4);
    unsigned char* selmask = (unsigned char*)alloc((size_t)24 * 16384);
    unsigned short* lists = (unsigned short*)alloc((size_t)24 * 128 * 128 * 2);
    int* counts = (int*)alloc(24 * 128 * 4);
    float* low_out   = (float*)alloc((size_t)24 * 128 * 64 * 4);
    float* low_norm  = (float*)alloc(24 * 128 * 4);

    k_prep<<<256, 192, 0, stream>>>(X, mask, Xb, Xh, tc);
    k_convW<<<1728, 256, 0, stream>>>(Wq, Wk, Wv, Wb);
    k_gemm_qkv<<<dim3(32, 18), 256, 0, stream>>>(Xb, Wb, bq, bk, bv, mask, Qb, Kb, Vt);
    k_lowres<<<dim3(9, 32), 256, 0, stream>>>(Xh, tc, Wq, Wk, Wv, bq, bk, bv, Qh, Kh, Vh);
    k_lowlogit<<<dim3(24, 8), 256, 0, stream>>>(Qh, Kh, prior, rowmax);
    k_select<<<24, 1024, 0, stream>>>(prior, selmask, lists, counts);
    k_lowout<<<3072, 64, 0, stream>>>(prior, selmask, tc, Vh, low_out, low_norm);
    k_high<<<3072, 64, 0, stream>>>(Qb, Kb, Vt, counts, lists, rowmax, low_out,
                                    low_norm, mask, out);
}

// Round 6
// 338.328 us; speedup vs baseline: 1.3023x; 1.0139x over previous
//
#include <hip/hip_runtime.h>

typedef __bf16 bf16;
typedef float f32x4 __attribute__((ext_vector_type(4)));
typedef bf16 bf16x8 __attribute__((ext_vector_type(8)));
typedef bf16 bf16x4 __attribute__((ext_vector_type(4)));
typedef unsigned int uint;
typedef unsigned short ushort;

// Problem constants: B=2 S=4096 D=768 H=12 HD=64 BLK=32 NBR=128 MB=24 NUM_BLOCK=1024 DIAG_N=3

__device__ __forceinline__ void llds16(const bf16* g, bf16* l) {
    __builtin_amdgcn_global_load_lds((const __attribute__((address_space(1))) uint*)g,
                                     (__attribute__((address_space(3))) uint*)l, 16, 0, 0);
}

__device__ __forceinline__ uint sortable(float f) {
    uint u = __float_as_uint(f);
    return u ^ (uint)(((int)u >> 31) | 0x80000000);
}

// ---------------- fused prep: X->bf16 conversion + masked block sums + token counts ----
__global__ __launch_bounds__(192)
void k_prep(const float* __restrict__ X, const float* __restrict__ mask,
            bf16* __restrict__ Xb, float* __restrict__ Xh, float* __restrict__ tc) {
    const int row = blockIdx.x;                 // b*128 + nbr
    const int b = row >> 7, nbr = row & 127;
    const int t = threadIdx.x;                  // float4 column 0..191
    const float4* xp = (const float4*)(X + (size_t)(b * 4096 + nbr * 32) * 768) + t;
    bf16x4* xbp = (bf16x4*)(Xb + (size_t)(b * 4096 + nbr * 32) * 768) + t;
    const float* mp = mask + b * 4096 + nbr * 32;
    float4 s = {0.f, 0.f, 0.f, 0.f};
    float tcs = 0.f;
#pragma unroll 4
    for (int tok = 0; tok < 32; ++tok) {
        float4 v = xp[(size_t)tok * 192];
        float m = mp[tok];
        s.x += v.x * m; s.y += v.y * m; s.z += v.z * m; s.w += v.w * m;
        tcs += m;
        bf16x4 o = {(bf16)v.x, (bf16)v.y, (bf16)v.z, (bf16)v.w};
        xbp[(size_t)tok * 192] = o;
    }
    ((float4*)(Xh + (size_t)row * 768))[t] = s;
    if (t == 0) tc[row] = tcs;
}

__global__ void k_convW(const float* __restrict__ Wq, const float* __restrict__ Wk,
                        const float* __restrict__ Wv, bf16* __restrict__ Wb) {
    int i = blockIdx.x * 256 + threadIdx.x;          // over 2304*768/4
    if (i >= 442368) return;
    int n = (i << 2) / 768;
    int k = (i << 2) % 768;
    const float* W = n < 768 ? Wq : (n < 1536 ? Wk : Wv);
    int nn = n - (n < 768 ? 0 : (n < 1536 ? 768 : 1536));
    float4 f = *(const float4*)(W + (size_t)nn * 768 + k);
    bf16x4 o = {(bf16)f.x, (bf16)f.y, (bf16)f.z, (bf16)f.w};
    ((bf16x4*)Wb)[i] = o;
}

// ---------------- QKV projection GEMM (bf16 MFMA, 128x128 tile, BK=64, XOR swizzle) ----
// R5: back to m97-like residency config (32 KB LDS, ~164 regs) with explicit
// __launch_bounds__(256,3) -> 3 blocks/CU so barrier drains overlap across blocks.
__global__ __launch_bounds__(256, 3)
void k_gemm_qkv(const bf16* __restrict__ Xb, const bf16* __restrict__ Wb,
                const float* __restrict__ bq, const float* __restrict__ bk,
                const float* __restrict__ bv, const float* __restrict__ mask,
                bf16* __restrict__ Qb, bf16* __restrict__ Kb, bf16* __restrict__ Vt) {
    __shared__ bf16 As[128 * 64];
    __shared__ bf16 Bs[128 * 64];
    const int tid = threadIdx.x;
    const int wave = tid >> 6, lane = tid & 63;
    const int quad = lane >> 4, l16 = lane & 15;
    const int wr = wave >> 1, wc = wave & 1;
    const int m0 = blockIdx.x * 128, n0 = blockIdx.y * 128;
    const int srow = lane >> 3;                              // row within 8-row chunk
    const int sgcol = (((lane & 7) ^ (srow & 7)) << 3);      // swizzled source col

    f32x4 acc[4][4] = {};

    for (int k0 = 0; k0 < 768; k0 += 64) {
        __syncthreads();
#pragma unroll
        for (int it = 0; it < 4; ++it) {
            int R = wave * 32 + it * 8;
            llds16(Xb + (size_t)(m0 + R + srow) * 768 + k0 + sgcol, &As[R * 64]);
            llds16(Wb + (size_t)(n0 + R + srow) * 768 + k0 + sgcol, &Bs[R * 64]);
        }
        __syncthreads();
#pragma unroll
        for (int ks = 0; ks < 2; ++ks) {
            const int pg = ((ks * 4 + quad) ^ (l16 & 7)) << 3;  // physical group offset
            bf16x8 a[4], b[4];
#pragma unroll
            for (int i = 0; i < 4; ++i)
                a[i] = *(const bf16x8*)&As[(wr * 64 + i * 16 + l16) * 64 + pg];
#pragma unroll
            for (int i = 0; i < 4; ++i)
                b[i] = *(const bf16x8*)&Bs[(wc * 64 + i * 16 + l16) * 64 + pg];
#pragma unroll
            for (int i = 0; i < 4; ++i)
#pragma unroll
                for (int j = 0; j < 4; ++j)
                    acc[i][j] = __builtin_amdgcn_mfma_f32_16x16x32_bf16(a[i], b[j], acc[i][j], 0, 0, 0);
        }
    }

    const int which = n0 / 768;                       // uniform per block
    const float* bias = which == 0 ? bq : (which == 1 ? bk : bv);
#pragma unroll
    for (int i = 0; i < 4; ++i) {
        int mrow = m0 + wr * 64 + i * 16 + quad * 4;
#pragma unroll
        for (int j = 0; j < 4; ++j) {
            int n = n0 + wc * 64 + j * 16 + l16;
            int hcol = n - which * 768;
            int h = hcol >> 6, d = hcol & 63;
#pragma unroll
            for (int r = 0; r < 4; ++r) {
                int mm = mrow + r;
                int bidx = mm >> 12, s = mm & 4095;
                float y = (acc[i][j][r] + bias[hcol]) * mask[(bidx << 12) + s];
                bf16 v = (bf16)y;
                size_t mb = (size_t)(bidx * 12 + h);
                if (which == 0)      Qb[((mb << 12) + s) * 64 + d] = v;
                else if (which == 1) Kb[((mb << 12) + s) * 64 + d] = v;
                else                 Vt[((mb * 128 + (s >> 5)) * 64 + d) * 32 + (s & 31)] = v;
            }
        }
    }
}

// ---------------- exact f32 low-res projections: Qh/Kh/Vh ----------------
__global__ __launch_bounds__(256)
void k_lowres(const float* __restrict__ Xh, const float* __restrict__ tc,
              const float* __restrict__ Wq, const float* __restrict__ Wk,
              const float* __restrict__ Wv, const float* __restrict__ bq,
              const float* __restrict__ bk, const float* __restrict__ bv,
              float* __restrict__ Qh, float* __restrict__ Kh, float* __restrict__ Vh) {
    int nb9 = blockIdx.x, rc = blockIdx.y, t = threadIdx.x;   // grid (9, 32)
    __shared__ float xsh[8 * 768];
    for (int idx = t; idx < 8 * 768; idx += 256)
        xsh[idx] = Xh[(size_t)(rc * 8) * 768 + idx];
    __syncthreads();
    int which = nb9 / 3;
    int wcol = (nb9 % 3) * 256 + t;
    const float* W = (which == 0 ? Wq : (which == 1 ? Wk : Wv)) + (size_t)wcol * 768;
    const float* bias = which == 0 ? bq : (which == 1 ? bk : bv);
    float acc[8] = {};
    for (int k = 0; k < 768; k += 4) {
        float4 w4 = *(const float4*)(W + k);
#pragma unroll
        for (int j = 0; j < 8; ++j) {
            float4 x4 = *(const float4*)&xsh[j * 768 + k];
            acc[j] += w4.x * x4.x + w4.y * x4.y + w4.z * x4.z + w4.w * x4.w;
        }
    }
    int h = wcol >> 6, d = wcol & 63;
    float bval = bias[wcol];
    float* dst = which == 0 ? Qh : (which == 1 ? Kh : Vh);
#pragma unroll
    for (int j = 0; j < 8; ++j) {
        int row = rc * 8 + j;
        int b = row >> 7, nbr = row & 127;
        float tcv = tc[row];
        float val = (acc[j] + tcv * bval) / (tcv + 1e-6f);
        dst[(((size_t)(b * 12 + h)) * 128 + nbr) * 64 + d] = val;
    }
}

// ---------------- low-res logits + row max (f32 exact) ----------------
__global__ __launch_bounds__(256)
void k_lowlogit(const float* __restrict__ Qh, const float* __restrict__ Kh,
                float* __restrict__ prior, float* __restrict__ rowmax) {
    int mb = blockIdx.x, rc = blockIdx.y;             // grid (24, 8)
    int tid = threadIdx.x;
    __shared__ float Ksh[64 * 132];                   // [k][c] padded
    __shared__ float Qsh[16 * 64];
    for (int idx = tid; idx < 128 * 64; idx += 256) {
        int c = idx >> 6, k = idx & 63;
        Ksh[k * 132 + c] = Kh[((size_t)mb * 128 + c) * 64 + k];
    }
    for (int idx = tid; idx < 16 * 64; idx += 256) {
        int r = idx >> 6, k = idx & 63;
        Qsh[idx] = Qh[((size_t)mb * 128 + rc * 16 + r) * 64 + k];
    }
    __syncthreads();
    int rloc = tid >> 4, cg = tid & 15;
    float acc[8] = {};
    for (int k = 0; k < 64; ++k) {
        float qv = Qsh[rloc * 64 + k];
        const float* kr = &Ksh[k * 132 + cg * 8];
#pragma unroll
        for (int j = 0; j < 8; ++j) acc[j] += qv * kr[j];
    }
    float pm = -3.4e38f;
#pragma unroll
    for (int j = 0; j < 8; ++j) { acc[j] *= 0.125f; pm = fmaxf(pm, acc[j]); }
#pragma unroll
    for (int d = 1; d < 16; d <<= 1) pm = fmaxf(pm, __shfl_xor(pm, d, 64));
    int r = rc * 16 + rloc;
    if (cg == 0) rowmax[mb * 128 + r] = pm;
    float* dst = prior + ((size_t)mb * 128 + r) * 128 + cg * 8;
#pragma unroll
    for (int j = 0; j < 8; ++j) dst[j] = acc[j] - pm;
}

// ---------------- exact top-1024 threshold + list build (2-bit radix descent) --------
// R5: also emits qorder[mb][rank] = q sorted by descending list count, so k_high
// can run longest rows first (load-balance; dispatch is roughly in-order).
__global__ __launch_bounds__(1024)
void k_select(const float* __restrict__ prior, unsigned char* __restrict__ selmask,
              unsigned short* __restrict__ lists, int* __restrict__ counts,
              ushort* __restrict__ qorder) {
    const int mb = blockIdx.x, tid = threadIdx.x;
    const int ln = tid & 63;
    __shared__ int lc[16 * 3];                 // [level][field 3,2,1] counts
    __shared__ int cnt[128];
    if (tid < 48) lc[tid] = 0;
    if (tid < 128) cnt[tid] = 0;

    const int r = tid >> 3;                    // row (q-block) index, 8 threads/row
    const int cbase = (tid & 7) << 4;          // starting column
    uint key[16];
    const float4* P4 = (const float4*)(prior + (size_t)mb * 16384) + (tid << 2);
#pragma unroll
    for (int j4 = 0; j4 < 4; ++j4) {
        float4 v = P4[j4];
        float vv[4] = {v.x, v.y, v.z, v.w};
#pragma unroll
        for (int e = 0; e < 4; ++e) {
            int c = cbase + (j4 << 2) + e;
            float f = vv[e] + ((r - c <= 1 && c - r <= 1) ? 5e3f : 0.f);
            key[(j4 << 2) + e] = sortable(f);
        }
    }
    __syncthreads();                           // lc/cnt zeroed before use

    uint pfx = 0u;
    int k = 1024;
#pragma unroll
    for (int lvl = 0; lvl < 16; ++lvl) {
        const int sh = 30 - 2 * lvl;
        const uint maskA = (lvl == 0) ? 0u : (0xFFFFFFFFu << (sh + 2));
        int c3 = 0, c2 = 0, c1 = 0;
#pragma unroll
        for (int j = 0; j < 16; ++j) {
            uint x = key[j];
            bool m = ((x ^ pfx) & maskA) == 0u;
            uint f = (x >> sh) & 3u;
            c3 += (m && f == 3u);
            c2 += (m && f == 2u);
            c1 += (m && f == 1u);
        }
#pragma unroll
        for (int d = 1; d < 64; d <<= 1) {
            c3 += __shfl_xor(c3, d, 64);
            c2 += __shfl_xor(c2, d, 64);
            c1 += __shfl_xor(c1, d, 64);
        }
        if (ln == 0) {
            atomicAdd(&lc[lvl * 3 + 0], c3);
            atomicAdd(&lc[lvl * 3 + 1], c2);
            atomicAdd(&lc[lvl * 3 + 2], c1);
        }
        __syncthreads();
        const int C3 = lc[lvl * 3 + 0], C2 = lc[lvl * 3 + 1], C1 = lc[lvl * 3 + 2];
        uint choose;
        if (C3 >= k)                { choose = 3u; }
        else if (C3 + C2 >= k)      { choose = 2u; k -= C3; }
        else if (C3 + C2 + C1 >= k) { choose = 1u; k -= C3 + C2; }
        else                        { choose = 0u; k -= C3 + C2 + C1; }
        pfx |= choose << sh;
    }
    const uint T = pfx;                        // exact bit pattern of 1024th-largest prior

    uint packed[4] = {0u, 0u, 0u, 0u};
#pragma unroll
    for (int j = 0; j < 16; ++j) {
        if (key[j] >= T) {
            packed[j >> 2] |= 1u << ((j & 3) << 3);
            int pos = atomicAdd(&cnt[r], 1);
            lists[((size_t)mb * 128 + r) * 128 + pos] = (unsigned short)(cbase + j);
        }
    }
    uint4 pk;
    pk.x = packed[0]; pk.y = packed[1]; pk.z = packed[2]; pk.w = packed[3];
    *(uint4*)(selmask + (size_t)mb * 16384 + (size_t)tid * 16) = pk;
    __syncthreads();
    if (tid < 128) {
        const int myc = cnt[tid];
        counts[mb * 128 + tid] = myc;
        int rank = 0;
        for (int j = 0; j < 128; ++j) {        // broadcast LDS reads, O(128) per thread
            int cj = cnt[j];
            rank += (cj > myc) || (cj == myc && j < tid);
        }
        qorder[mb * 128 + rank] = (ushort)tid;
    }
}

// ---------------- low-res attention over non-selected blocks ----------------
__global__ __launch_bounds__(64)
void k_lowout(const float* __restrict__ prior, const unsigned char* __restrict__ selmask,
              const float* __restrict__ tc, const float* __restrict__ Vh,
              float* __restrict__ low_out, float* __restrict__ low_norm) {
    const int q = blockIdx.x & 127, mb = blockIdx.x >> 7;
    const int d = threadIdx.x;
    const float* pn = prior + ((size_t)mb * 128 + q) * 128;
    const uint4* smv = (const uint4*)(selmask + ((size_t)mb * 128 + q) * 128);
    uint sm32[32];
#pragma unroll
    for (int w = 0; w < 8; ++w) {
        uint4 u = smv[w];
        sm32[w * 4 + 0] = u.x; sm32[w * 4 + 1] = u.y;
        sm32[w * 4 + 2] = u.z; sm32[w * 4 + 3] = u.w;
    }
    const float* tcb = tc + (mb / 12) * 128;
    const float* Vb = Vh + (size_t)mb * 128 * 64;
    float acc = 0.f, nrm = 0.f;
#pragma unroll 4
    for (int c = 0; c < 128; ++c) {
        if (!((sm32[c >> 2] >> ((c & 3) << 3)) & 1u)) {
            float w = __expf(pn[c]) * tcb[c];
            acc += w * Vb[c * 64 + d];
            nrm += w;
        }
    }
    low_out[((size_t)mb * 128 + q) * 64 + d] = acc;
    if (d == 0) low_norm[mb * 128 + q] = nrm;
}

// ---------------- high-res sparse attention + fused combine epilogue ----------------
// One wave per (mb, q-block) with q taken from qorder (longest lists first);
// K/V register prefetch; combine epilogue writes final `out`.
__global__ __launch_bounds__(64)
void k_high(const bf16* __restrict__ Qb, const bf16* __restrict__ Kb,
            const bf16* __restrict__ Vt, const int* __restrict__ counts,
            const unsigned short* __restrict__ lists, const ushort* __restrict__ qorder,
            const float* __restrict__ rowmax, const float* __restrict__ low_out,
            const float* __restrict__ low_norm, const float* __restrict__ mask,
            float* __restrict__ out) {
    const int mb = blockIdx.x >> 7;
    const int q = qorder[mb * 128 + (blockIdx.x & 127)];
    const int lane = threadIdx.x, quad = lane >> 4, l16 = lane & 15;
    __shared__ bf16 Pb[32 * 40];

    const bf16* Qbase = Qb + ((size_t)mb * 4096 + q * 32) * 64;
    bf16x8 qf[2][2];
#pragma unroll
    for (int mt = 0; mt < 2; ++mt)
#pragma unroll
        for (int ks = 0; ks < 2; ++ks)
            qf[mt][ks] = *(const bf16x8*)(Qbase + (mt * 16 + l16) * 64 + ks * 32 + quad * 8);

    float m_st[2][4], l_st[2][4];
    f32x4 o[2][4] = {};
#pragma unroll
    for (int mt = 0; mt < 2; ++mt)
#pragma unroll
        for (int r = 0; r < 4; ++r) { m_st[mt][r] = -1e30f; l_st[mt][r] = 0.f; }

    int cntv = counts[mb * 128 + q];
    if (cntv > 128) cntv = 128;
    if (cntv < 1) cntv = 1;                            // diag band guarantees >=1
    const unsigned short* lst = lists + ((size_t)mb * 128 + q) * 128;

    const bf16* KB = Kb + (size_t)mb * 4096 * 64;
    const bf16* VB = Vt + (size_t)mb * 128 * 2048;

    int c0 = lst[0];
    bf16x8 kf_n[2][2], vf_n[4];
#pragma unroll
    for (int nt = 0; nt < 2; ++nt)
#pragma unroll
        for (int ks = 0; ks < 2; ++ks)
            kf_n[nt][ks] = *(const bf16x8*)(KB + ((size_t)c0 * 32 + nt * 16 + l16) * 64 + ks * 32 + quad * 8);
#pragma unroll
    for (int nd = 0; nd < 4; ++nd)
        vf_n[nd] = *(const bf16x8*)(VB + (size_t)c0 * 2048 + (nd * 16 + l16) * 32 + quad * 8);

    for (int i = 0; i < cntv; ++i) {
        bf16x8 kf[2][2], vf[4];
#pragma unroll
        for (int nt = 0; nt < 2; ++nt)
#pragma unroll
            for (int ks = 0; ks < 2; ++ks) kf[nt][ks] = kf_n[nt][ks];
#pragma unroll
        for (int nd = 0; nd < 4; ++nd) vf[nd] = vf_n[nd];

        if (i + 1 < cntv) {                            // prefetch next block
            const int cn = lst[i + 1];
#pragma unroll
            for (int nt = 0; nt < 2; ++nt)
#pragma unroll
                for (int ks = 0; ks < 2; ++ks)
                    kf_n[nt][ks] = *(const bf16x8*)(KB + ((size_t)cn * 32 + nt * 16 + l16) * 64 + ks * 32 + quad * 8);
#pragma unroll
            for (int nd = 0; nd < 4; ++nd)
                vf_n[nd] = *(const bf16x8*)(VB + (size_t)cn * 2048 + (nd * 16 + l16) * 32 + quad * 8);
        }

        f32x4 sf[2][2] = {};
#pragma unroll
        for (int mt = 0; mt < 2; ++mt)
#pragma unroll
            for (int nt = 0; nt < 2; ++nt) {
                sf[mt][nt] = __builtin_amdgcn_mfma_f32_16x16x32_bf16(qf[mt][0], kf[nt][0], sf[mt][nt], 0, 0, 0);
                sf[mt][nt] = __builtin_amdgcn_mfma_f32_16x16x32_bf16(qf[mt][1], kf[nt][1], sf[mt][nt], 0, 0, 0);
                sf[mt][nt] *= 0.125f;
            }

        float rmx[2][4];
#pragma unroll
        for (int mt = 0; mt < 2; ++mt)
#pragma unroll
            for (int r = 0; r < 4; ++r)
                rmx[mt][r] = fmaxf(sf[mt][0][r], sf[mt][1][r]);
#pragma unroll
        for (int d = 1; d < 16; d <<= 1)
#pragma unroll
            for (int mt = 0; mt < 2; ++mt)
#pragma unroll
                for (int r = 0; r < 4; ++r)
                    rmx[mt][r] = fmaxf(rmx[mt][r], __shfl_xor(rmx[mt][r], d, 64));

        float alpha[2][4], rs[2][4];
#pragma unroll
        for (int mt = 0; mt < 2; ++mt)
#pragma unroll
            for (int r = 0; r < 4; ++r) {
                float mn = fmaxf(m_st[mt][r], rmx[mt][r]);
                alpha[mt][r] = __expf(m_st[mt][r] - mn);
                m_st[mt][r] = mn;
                rs[mt][r] = 0.f;
            }
#pragma unroll
        for (int mt = 0; mt < 2; ++mt)
#pragma unroll
            for (int nt = 0; nt < 2; ++nt)
#pragma unroll
                for (int r = 0; r < 4; ++r) {
                    float p = __expf(sf[mt][nt][r] - m_st[mt][r]);
                    rs[mt][r] += p;
                    Pb[(mt * 16 + quad * 4 + r) * 40 + nt * 16 + l16] = (bf16)p;
                }
#pragma unroll
        for (int d = 1; d < 16; d <<= 1)
#pragma unroll
            for (int mt = 0; mt < 2; ++mt)
#pragma unroll
                for (int r = 0; r < 4; ++r)
                    rs[mt][r] += __shfl_xor(rs[mt][r], d, 64);
#pragma unroll
        for (int mt = 0; mt < 2; ++mt)
#pragma unroll
            for (int r = 0; r < 4; ++r)
                l_st[mt][r] = l_st[mt][r] * alpha[mt][r] + rs[mt][r];
#pragma unroll
        for (int mt = 0; mt < 2; ++mt)
#pragma unroll
            for (int nd = 0; nd < 4; ++nd)
#pragma unroll
                for (int r = 0; r < 4; ++r)
                    o[mt][nd][r] *= alpha[mt][r];

        __syncthreads();                               // Pb writes -> A-frag reads (1 wave)
        bf16x8 pf[2];
#pragma unroll
        for (int mt = 0; mt < 2; ++mt)
            pf[mt] = *(const bf16x8*)&Pb[(mt * 16 + l16) * 40 + quad * 8];
#pragma unroll
        for (int mt = 0; mt < 2; ++mt)
#pragma unroll
            for (int nd = 0; nd < 4; ++nd)
                o[mt][nd] = __builtin_amdgcn_mfma_f32_16x16x32_bf16(pf[mt], vf[nd], o[mt][nd], 0, 0, 0);
        __syncthreads();
    }

    // ---- fused combine epilogue ----
    const int b = mb / 12, h = mb - b * 12;
    const float rm = rowmax[mb * 128 + q];
    const float ln = low_norm[mb * 128 + q];
    const float* LO = low_out + ((size_t)mb * 128 + q) * 64;
#pragma unroll
    for (int mt = 0; mt < 2; ++mt)
#pragma unroll
        for (int r = 0; r < 4; ++r) {
            const int s = q * 32 + mt * 16 + quad * 4 + r;
            const float mv = fmaxf(m_st[mt][r], -1e6f);
            const float hn = l_st[mt][r];
            const float mk = mask[(b << 12) + s];
            const float lcr = (rm - mv) * mk;
            const float lcf = __expf(fminf(lcr, 0.f));
            const float hcf = __expf(-fmaxf(lcr, 0.f));
            const float den = 1.0f / (hn * hcf + ln * lcf + 1e-6f);
            float* op = out + ((size_t)(b * 4096 + s)) * 768 + h * 64;
#pragma unroll
            for (int nd = 0; nd < 4; ++nd) {
                const int d = nd * 16 + l16;
                op[d] = (o[mt][nd][r] * hcf + LO[d] * lcf) * den;
            }
        }
}

extern "C" void kernel_launch(void* const* d_in, const int* in_sizes, int n_in,
                              void* d_out, int out_size, void* d_ws, size_t ws_size,
                              hipStream_t stream) {
    (void)in_sizes; (void)n_in; (void)out_size; (void)ws_size;
    const float* X    = (const float*)d_in[0];
    const float* mask = (const float*)d_in[1];
    const float* Wq   = (const float*)d_in[2];
    const float* bq   = (const float*)d_in[3];
    const float* Wk   = (const float*)d_in[4];
    const float* bk   = (const float*)d_in[5];
    const float* Wv   = (const float*)d_in[6];
    const float* bv   = (const float*)d_in[7];
    float* out = (float*)d_out;

    char* ws = (char*)d_ws;
    size_t off = 0;
    auto alloc = [&](size_t bytes) -> void* {
        off = (off + 255) & ~(size_t)255;
        void* p = ws + off;
        off += bytes;
        return p;
    };
    bf16* Xb  = (bf16*)alloc((size_t)8192 * 768 * 2);
    bf16* Wb  = (bf16*)alloc((size_t)2304 * 768 * 2);
    bf16* Qb  = (bf16*)alloc((size_t)24 * 4096 * 64 * 2);
    bf16* Kb  = (bf16*)alloc((size_t)24 * 4096 * 64 * 2);
    bf16* Vt  = (bf16*)alloc((size_t)24 * 4096 * 64 * 2);
    float* Xh = (float*)alloc((size_t)256 * 768 * 4);
    float* tc = (float*)alloc(256 * 4);
    float* Qh = (float*)alloc((size_t)24 * 128 * 64 * 4);
    float* Kh = (float*)alloc((size_t)24 * 128 * 64 * 4);
    float* Vh = (float*)alloc((size_t)24 * 128 * 64 * 4);
    float* prior = (float*)alloc((size_t)24 * 16384 * 4);
    float* rowmax = (float*)alloc(24 * 128 * 4);
    unsigned char* selmask = (unsigned char*)alloc((size_t)24 * 16384);
    unsigned short* lists = (unsigned short*)alloc((size_t)24 * 128 * 128 * 2);
    int* counts = (int*)alloc(24 * 128 * 4);
    ushort* qorder = (ushort*)alloc(24 * 128 * 2);
    float* low_out   = (float*)alloc((size_t)24 * 128 * 64 * 4);
    float* low_norm  = (float*)alloc(24 * 128 * 4);

    k_prep<<<256, 192, 0, stream>>>(X, mask, Xb, Xh, tc);
    k_convW<<<1728, 256, 0, stream>>>(Wq, Wk, Wv, Wb);
    k_gemm_qkv<<<dim3(64, 18), 256, 0, stream>>>(Xb, Wb, bq, bk, bv, mask, Qb, Kb, Vt);
    k_lowres<<<dim3(9, 32), 256, 0, stream>>>(Xh, tc, Wq, Wk, Wv, bq, bk, bv, Qh, Kh, Vh);
    k_lowlogit<<<dim3(24, 8), 256, 0, stream>>>(Qh, Kh, prior, rowmax);
    k_select<<<24, 1024, 0, stream>>>(prior, selmask, lists, counts, qorder);
    k_lowout<<<3072, 64, 0, stream>>>(prior, selmask, tc, Vh, low_out, low_norm);
    k_high<<<3072, 64, 0, stream>>>(Qb, Kb, Vt, counts, lists, qorder, rowmax, low_out,
                                    low_norm, mask, out);
}

// Round 7
// 334.719 us; speedup vs baseline: 1.3163x; 1.0108x over previous
//
#include <hip/hip_runtime.h>

typedef __bf16 bf16;
typedef float f32x4 __attribute__((ext_vector_type(4)));
typedef bf16 bf16x8 __attribute__((ext_vector_type(8)));
typedef bf16 bf16x4 __attribute__((ext_vector_type(4)));
typedef unsigned int uint;
typedef unsigned short ushort;

// Problem constants: B=2 S=4096 D=768 H=12 HD=64 BLK=32 NBR=128 MB=24 NUM_BLOCK=1024 DIAG_N=3

__device__ __forceinline__ void llds16(const bf16* g, bf16* l) {
    __builtin_amdgcn_global_load_lds((const __attribute__((address_space(1))) uint*)g,
                                     (__attribute__((address_space(3))) uint*)l, 16, 0, 0);
}

__device__ __forceinline__ uint sortable(float f) {
    uint u = __float_as_uint(f);
    return u ^ (uint)(((int)u >> 31) | 0x80000000);
}

// ---------------- fused prep: X->bf16 conversion + masked block sums + token counts ----
__global__ __launch_bounds__(192)
void k_prep(const float* __restrict__ X, const float* __restrict__ mask,
            bf16* __restrict__ Xb, float* __restrict__ Xh, float* __restrict__ tc) {
    const int row = blockIdx.x;                 // b*128 + nbr
    const int b = row >> 7, nbr = row & 127;
    const int t = threadIdx.x;                  // float4 column 0..191
    const float4* xp = (const float4*)(X + (size_t)(b * 4096 + nbr * 32) * 768) + t;
    bf16x4* xbp = (bf16x4*)(Xb + (size_t)(b * 4096 + nbr * 32) * 768) + t;
    const float* mp = mask + b * 4096 + nbr * 32;
    float4 s = {0.f, 0.f, 0.f, 0.f};
    float tcs = 0.f;
#pragma unroll 4
    for (int tok = 0; tok < 32; ++tok) {
        float4 v = xp[(size_t)tok * 192];
        float m = mp[tok];
        s.x += v.x * m; s.y += v.y * m; s.z += v.z * m; s.w += v.w * m;
        tcs += m;
        bf16x4 o = {(bf16)v.x, (bf16)v.y, (bf16)v.z, (bf16)v.w};
        xbp[(size_t)tok * 192] = o;
    }
    ((float4*)(Xh + (size_t)row * 768))[t] = s;
    if (t == 0) tc[row] = tcs;
}

__global__ void k_convW(const float* __restrict__ Wq, const float* __restrict__ Wk,
                        const float* __restrict__ Wv, bf16* __restrict__ Wb) {
    int i = blockIdx.x * 256 + threadIdx.x;          // over 2304*768/4
    if (i >= 442368) return;
    int n = (i << 2) / 768;
    int k = (i << 2) % 768;
    const float* W = n < 768 ? Wq : (n < 1536 ? Wk : Wv);
    int nn = n - (n < 768 ? 0 : (n < 1536 ? 768 : 1536));
    float4 f = *(const float4*)(W + (size_t)nn * 768 + k);
    bf16x4 o = {(bf16)f.x, (bf16)f.y, (bf16)f.z, (bf16)f.w};
    ((bf16x4*)Wb)[i] = o;
}

// ---------------- QKV projection GEMM (bf16 MFMA, 128x128 tile, BK=64, XOR swizzle) ----
__global__ __launch_bounds__(256, 3)
void k_gemm_qkv(const bf16* __restrict__ Xb, const bf16* __restrict__ Wb,
                const float* __restrict__ bq, const float* __restrict__ bk,
                const float* __restrict__ bv, const float* __restrict__ mask,
                bf16* __restrict__ Qb, bf16* __restrict__ Kb, bf16* __restrict__ Vt) {
    __shared__ bf16 As[128 * 64];
    __shared__ bf16 Bs[128 * 64];
    const int tid = threadIdx.x;
    const int wave = tid >> 6, lane = tid & 63;
    const int quad = lane >> 4, l16 = lane & 15;
    const int wr = wave >> 1, wc = wave & 1;
    const int m0 = blockIdx.x * 128, n0 = blockIdx.y * 128;
    const int srow = lane >> 3;                              // row within 8-row chunk
    const int sgcol = (((lane & 7) ^ (srow & 7)) << 3);      // swizzled source col

    f32x4 acc[4][4] = {};

    for (int k0 = 0; k0 < 768; k0 += 64) {
        __syncthreads();
#pragma unroll
        for (int it = 0; it < 4; ++it) {
            int R = wave * 32 + it * 8;
            llds16(Xb + (size_t)(m0 + R + srow) * 768 + k0 + sgcol, &As[R * 64]);
            llds16(Wb + (size_t)(n0 + R + srow) * 768 + k0 + sgcol, &Bs[R * 64]);
        }
        __syncthreads();
#pragma unroll
        for (int ks = 0; ks < 2; ++ks) {
            const int pg = ((ks * 4 + quad) ^ (l16 & 7)) << 3;  // physical group offset
            bf16x8 a[4], b[4];
#pragma unroll
            for (int i = 0; i < 4; ++i)
                a[i] = *(const bf16x8*)&As[(wr * 64 + i * 16 + l16) * 64 + pg];
#pragma unroll
            for (int i = 0; i < 4; ++i)
                b[i] = *(const bf16x8*)&Bs[(wc * 64 + i * 16 + l16) * 64 + pg];
#pragma unroll
            for (int i = 0; i < 4; ++i)
#pragma unroll
                for (int j = 0; j < 4; ++j)
                    acc[i][j] = __builtin_amdgcn_mfma_f32_16x16x32_bf16(a[i], b[j], acc[i][j], 0, 0, 0);
        }
    }

    const int which = n0 / 768;                       // uniform per block
    const float* bias = which == 0 ? bq : (which == 1 ? bk : bv);
#pragma unroll
    for (int i = 0; i < 4; ++i) {
        int mrow = m0 + wr * 64 + i * 16 + quad * 4;
#pragma unroll
        for (int j = 0; j < 4; ++j) {
            int n = n0 + wc * 64 + j * 16 + l16;
            int hcol = n - which * 768;
            int h = hcol >> 6, d = hcol & 63;
#pragma unroll
            for (int r = 0; r < 4; ++r) {
                int mm = mrow + r;
                int bidx = mm >> 12, s = mm & 4095;
                float y = (acc[i][j][r] + bias[hcol]) * mask[(bidx << 12) + s];
                bf16 v = (bf16)y;
                size_t mb = (size_t)(bidx * 12 + h);
                if (which == 0)      Qb[((mb << 12) + s) * 64 + d] = v;
                else if (which == 1) Kb[((mb << 12) + s) * 64 + d] = v;
                else                 Vt[((mb * 128 + (s >> 5)) * 64 + d) * 32 + (s & 31)] = v;
            }
        }
    }
}

// ---------------- exact f32 low-res projections: Qh/Kh/Vh ----------------
__global__ __launch_bounds__(256)
void k_lowres(const float* __restrict__ Xh, const float* __restrict__ tc,
              const float* __restrict__ Wq, const float* __restrict__ Wk,
              const float* __restrict__ Wv, const float* __restrict__ bq,
              const float* __restrict__ bk, const float* __restrict__ bv,
              float* __restrict__ Qh, float* __restrict__ Kh, float* __restrict__ Vh) {
    int nb9 = blockIdx.x, rc = blockIdx.y, t = threadIdx.x;   // grid (9, 32)
    __shared__ float xsh[8 * 768];
    for (int idx = t; idx < 8 * 768; idx += 256)
        xsh[idx] = Xh[(size_t)(rc * 8) * 768 + idx];
    __syncthreads();
    int which = nb9 / 3;
    int wcol = (nb9 % 3) * 256 + t;
    const float* W = (which == 0 ? Wq : (which == 1 ? Wk : Wv)) + (size_t)wcol * 768;
    const float* bias = which == 0 ? bq : (which == 1 ? bk : bv);
    float acc[8] = {};
    for (int k = 0; k < 768; k += 4) {
        float4 w4 = *(const float4*)(W + k);
#pragma unroll
        for (int j = 0; j < 8; ++j) {
            float4 x4 = *(const float4*)&xsh[j * 768 + k];
            acc[j] += w4.x * x4.x + w4.y * x4.y + w4.z * x4.z + w4.w * x4.w;
        }
    }
    int h = wcol >> 6, d = wcol & 63;
    float bval = bias[wcol];
    float* dst = which == 0 ? Qh : (which == 1 ? Kh : Vh);
#pragma unroll
    for (int j = 0; j < 8; ++j) {
        int row = rc * 8 + j;
        int b = row >> 7, nbr = row & 127;
        float tcv = tc[row];
        float val = (acc[j] + tcv * bval) / (tcv + 1e-6f);
        dst[(((size_t)(b * 12 + h)) * 128 + nbr) * 64 + d] = val;
    }
}

// ---------------- low-res logits + row max (f32 exact) ----------------
__global__ __launch_bounds__(256)
void k_lowlogit(const float* __restrict__ Qh, const float* __restrict__ Kh,
                float* __restrict__ prior, float* __restrict__ rowmax) {
    int mb = blockIdx.x, rc = blockIdx.y;             // grid (24, 8)
    int tid = threadIdx.x;
    __shared__ float Ksh[64 * 132];                   // [k][c] padded
    __shared__ float Qsh[16 * 64];
    for (int idx = tid; idx < 128 * 64; idx += 256) {
        int c = idx >> 6, k = idx & 63;
        Ksh[k * 132 + c] = Kh[((size_t)mb * 128 + c) * 64 + k];
    }
    for (int idx = tid; idx < 16 * 64; idx += 256) {
        int r = idx >> 6, k = idx & 63;
        Qsh[idx] = Qh[((size_t)mb * 128 + rc * 16 + r) * 64 + k];
    }
    __syncthreads();
    int rloc = tid >> 4, cg = tid & 15;
    float acc[8] = {};
    for (int k = 0; k < 64; ++k) {
        float qv = Qsh[rloc * 64 + k];
        const float* kr = &Ksh[k * 132 + cg * 8];
#pragma unroll
        for (int j = 0; j < 8; ++j) acc[j] += qv * kr[j];
    }
    float pm = -3.4e38f;
#pragma unroll
    for (int j = 0; j < 8; ++j) { acc[j] *= 0.125f; pm = fmaxf(pm, acc[j]); }
#pragma unroll
    for (int d = 1; d < 16; d <<= 1) pm = fmaxf(pm, __shfl_xor(pm, d, 64));
    int r = rc * 16 + rloc;
    if (cg == 0) rowmax[mb * 128 + r] = pm;
    float* dst = prior + ((size_t)mb * 128 + r) * 128 + cg * 8;
#pragma unroll
    for (int j = 0; j < 8; ++j) dst[j] = acc[j] - pm;
}

// ---------------- exact top-1024 threshold + list build (2-bit radix descent) --------
__global__ __launch_bounds__(1024)
void k_select(const float* __restrict__ prior, unsigned char* __restrict__ selmask,
              unsigned short* __restrict__ lists, int* __restrict__ counts,
              ushort* __restrict__ qorder) {
    const int mb = blockIdx.x, tid = threadIdx.x;
    const int ln = tid & 63;
    __shared__ int lc[16 * 3];                 // [level][field 3,2,1] counts
    __shared__ int cnt[128];
    if (tid < 48) lc[tid] = 0;
    if (tid < 128) cnt[tid] = 0;

    const int r = tid >> 3;                    // row (q-block) index, 8 threads/row
    const int cbase = (tid & 7) << 4;          // starting column
    uint key[16];
    const float4* P4 = (const float4*)(prior + (size_t)mb * 16384) + (tid << 2);
#pragma unroll
    for (int j4 = 0; j4 < 4; ++j4) {
        float4 v = P4[j4];
        float vv[4] = {v.x, v.y, v.z, v.w};
#pragma unroll
        for (int e = 0; e < 4; ++e) {
            int c = cbase + (j4 << 2) + e;
            float f = vv[e] + ((r - c <= 1 && c - r <= 1) ? 5e3f : 0.f);
            key[(j4 << 2) + e] = sortable(f);
        }
    }
    __syncthreads();                           // lc/cnt zeroed before use

    uint pfx = 0u;
    int k = 1024;
#pragma unroll
    for (int lvl = 0; lvl < 16; ++lvl) {
        const int sh = 30 - 2 * lvl;
        const uint maskA = (lvl == 0) ? 0u : (0xFFFFFFFFu << (sh + 2));
        int c3 = 0, c2 = 0, c1 = 0;
#pragma unroll
        for (int j = 0; j < 16; ++j) {
            uint x = key[j];
            bool m = ((x ^ pfx) & maskA) == 0u;
            uint f = (x >> sh) & 3u;
            c3 += (m && f == 3u);
            c2 += (m && f == 2u);
            c1 += (m && f == 1u);
        }
#pragma unroll
        for (int d = 1; d < 64; d <<= 1) {
            c3 += __shfl_xor(c3, d, 64);
            c2 += __shfl_xor(c2, d, 64);
            c1 += __shfl_xor(c1, d, 64);
        }
        if (ln == 0) {
            atomicAdd(&lc[lvl * 3 + 0], c3);
            atomicAdd(&lc[lvl * 3 + 1], c2);
            atomicAdd(&lc[lvl * 3 + 2], c1);
        }
        __syncthreads();
        const int C3 = lc[lvl * 3 + 0], C2 = lc[lvl * 3 + 1], C1 = lc[lvl * 3 + 2];
        uint choose;
        if (C3 >= k)                { choose = 3u; }
        else if (C3 + C2 >= k)      { choose = 2u; k -= C3; }
        else if (C3 + C2 + C1 >= k) { choose = 1u; k -= C3 + C2; }
        else                        { choose = 0u; k -= C3 + C2 + C1; }
        pfx |= choose << sh;
    }
    const uint T = pfx;                        // exact bit pattern of 1024th-largest prior

    uint packed[4] = {0u, 0u, 0u, 0u};
#pragma unroll
    for (int j = 0; j < 16; ++j) {
        if (key[j] >= T) {
            packed[j >> 2] |= 1u << ((j & 3) << 3);
            int pos = atomicAdd(&cnt[r], 1);
            lists[((size_t)mb * 128 + r) * 128 + pos] = (unsigned short)(cbase + j);
        }
    }
    uint4 pk;
    pk.x = packed[0]; pk.y = packed[1]; pk.z = packed[2]; pk.w = packed[3];
    *(uint4*)(selmask + (size_t)mb * 16384 + (size_t)tid * 16) = pk;
    __syncthreads();
    if (tid < 128) {
        const int myc = cnt[tid];
        counts[mb * 128 + tid] = myc;
        int rank = 0;
        for (int j = 0; j < 128; ++j) {        // broadcast LDS reads, O(128) per thread
            int cj = cnt[j];
            rank += (cj > myc) || (cj == myc && j < tid);
        }
        qorder[mb * 128 + rank] = (ushort)tid;
    }
}

// ---------------- low-res attention over non-selected blocks ----------------
__global__ __launch_bounds__(64)
void k_lowout(const float* __restrict__ prior, const unsigned char* __restrict__ selmask,
              const float* __restrict__ tc, const float* __restrict__ Vh,
              float* __restrict__ low_out, float* __restrict__ low_norm) {
    const int q = blockIdx.x & 127, mb = blockIdx.x >> 7;
    const int d = threadIdx.x;
    const float* pn = prior + ((size_t)mb * 128 + q) * 128;
    const uint4* smv = (const uint4*)(selmask + ((size_t)mb * 128 + q) * 128);
    uint sm32[32];
#pragma unroll
    for (int w = 0; w < 8; ++w) {
        uint4 u = smv[w];
        sm32[w * 4 + 0] = u.x; sm32[w * 4 + 1] = u.y;
        sm32[w * 4 + 2] = u.z; sm32[w * 4 + 3] = u.w;
    }
    const float* tcb = tc + (mb / 12) * 128;
    const float* Vb = Vh + (size_t)mb * 128 * 64;
    float acc = 0.f, nrm = 0.f;
#pragma unroll 4
    for (int c = 0; c < 128; ++c) {
        if (!((sm32[c >> 2] >> ((c & 3) << 3)) & 1u)) {
            float w = __expf(pn[c]) * tcb[c];
            acc += w * Vb[c * 64 + d];
            nrm += w;
        }
    }
    low_out[((size_t)mb * 128 + q) * 64 + d] = acc;
    if (d == 0) low_norm[mb * 128 + q] = nrm;
}

// ---------------- high-res sparse attention + fused combine epilogue ----------------
// R6: deferred-max fixed-shift softmax. Per iteration: QK MFMA -> per-lane raw max
// (8 fmax) -> P = exp2(sf*0.125*log2e) unshifted -> LDS -> PV MFMA + ones-column
// MFMA for the row-sum (l). No per-iter shuffle reductions, no rescale. Lane max is
// reduced once after the loop; epilogue folds exp(-mv) into the combine factor
// (hn*exp(-mv-max(lcr,0)) == reference hn_ref*hcf; *0.125 is exact so mv matches).
__global__ __launch_bounds__(64)
void k_high(const bf16* __restrict__ Qb, const bf16* __restrict__ Kb,
            const bf16* __restrict__ Vt, const int* __restrict__ counts,
            const unsigned short* __restrict__ lists, const ushort* __restrict__ qorder,
            const float* __restrict__ rowmax, const float* __restrict__ low_out,
            const float* __restrict__ low_norm, const float* __restrict__ mask,
            float* __restrict__ out) {
    const int mb = blockIdx.x >> 7;
    const int q = qorder[mb * 128 + (blockIdx.x & 127)];
    const int lane = threadIdx.x, quad = lane >> 4, l16 = lane & 15;
    __shared__ bf16 Pb[32 * 40];

    const bf16* Qbase = Qb + ((size_t)mb * 4096 + q * 32) * 64;
    bf16x8 qf[2][2];
#pragma unroll
    for (int mt = 0; mt < 2; ++mt)
#pragma unroll
        for (int ks = 0; ks < 2; ++ks)
            qf[mt][ks] = *(const bf16x8*)(Qbase + (mt * 16 + l16) * 64 + ks * 32 + quad * 8);

    bf16x8 ones;
#pragma unroll
    for (int j = 0; j < 8; ++j) ones[j] = (bf16)1.0f;

    float mxl[2][4];                                   // per-lane raw logit max
    f32x4 o[2][4] = {};
    f32x4 lac[2] = {};                                 // row-sum accumulator (ones-MFMA)
#pragma unroll
    for (int mt = 0; mt < 2; ++mt)
#pragma unroll
        for (int r = 0; r < 4; ++r) mxl[mt][r] = -3.4e38f;

    int cntv = counts[mb * 128 + q];
    if (cntv > 128) cntv = 128;
    if (cntv < 1) cntv = 1;                            // diag band guarantees >=1
    const unsigned short* lst = lists + ((size_t)mb * 128 + q) * 128;

    const bf16* KB = Kb + (size_t)mb * 4096 * 64;
    const bf16* VB = Vt + (size_t)mb * 128 * 2048;

    int c0 = lst[0];
    bf16x8 kf_n[2][2], vf_n[4];
#pragma unroll
    for (int nt = 0; nt < 2; ++nt)
#pragma unroll
        for (int ks = 0; ks < 2; ++ks)
            kf_n[nt][ks] = *(const bf16x8*)(KB + ((size_t)c0 * 32 + nt * 16 + l16) * 64 + ks * 32 + quad * 8);
#pragma unroll
    for (int nd = 0; nd < 4; ++nd)
        vf_n[nd] = *(const bf16x8*)(VB + (size_t)c0 * 2048 + (nd * 16 + l16) * 32 + quad * 8);

    for (int i = 0; i < cntv; ++i) {
        bf16x8 kf[2][2], vf[4];
#pragma unroll
        for (int nt = 0; nt < 2; ++nt)
#pragma unroll
            for (int ks = 0; ks < 2; ++ks) kf[nt][ks] = kf_n[nt][ks];
#pragma unroll
        for (int nd = 0; nd < 4; ++nd) vf[nd] = vf_n[nd];

        if (i + 1 < cntv) {                            // prefetch next block
            const int cn = lst[i + 1];
#pragma unroll
            for (int nt = 0; nt < 2; ++nt)
#pragma unroll
                for (int ks = 0; ks < 2; ++ks)
                    kf_n[nt][ks] = *(const bf16x8*)(KB + ((size_t)cn * 32 + nt * 16 + l16) * 64 + ks * 32 + quad * 8);
#pragma unroll
            for (int nd = 0; nd < 4; ++nd)
                vf_n[nd] = *(const bf16x8*)(VB + (size_t)cn * 2048 + (nd * 16 + l16) * 32 + quad * 8);
        }

        f32x4 sf[2][2] = {};
#pragma unroll
        for (int mt = 0; mt < 2; ++mt)
#pragma unroll
            for (int nt = 0; nt < 2; ++nt) {
                sf[mt][nt] = __builtin_amdgcn_mfma_f32_16x16x32_bf16(qf[mt][0], kf[nt][0], sf[mt][nt], 0, 0, 0);
                sf[mt][nt] = __builtin_amdgcn_mfma_f32_16x16x32_bf16(qf[mt][1], kf[nt][1], sf[mt][nt], 0, 0, 0);
            }

#pragma unroll
        for (int mt = 0; mt < 2; ++mt)
#pragma unroll
            for (int r = 0; r < 4; ++r) {
                mxl[mt][r] = fmaxf(mxl[mt][r], fmaxf(sf[mt][0][r], sf[mt][1][r]));
                // P = exp(0.125*raw) = 2^(raw * 0.125*log2e), unshifted
                Pb[(mt * 16 + quad * 4 + r) * 40 + 0 * 16 + l16] =
                    (bf16)exp2f(sf[mt][0][r] * 0.18033688011112042f);
                Pb[(mt * 16 + quad * 4 + r) * 40 + 1 * 16 + l16] =
                    (bf16)exp2f(sf[mt][1][r] * 0.18033688011112042f);
            }

        __syncthreads();                               // Pb writes -> A-frag reads (1 wave)
        bf16x8 pf[2];
#pragma unroll
        for (int mt = 0; mt < 2; ++mt)
            pf[mt] = *(const bf16x8*)&Pb[(mt * 16 + l16) * 40 + quad * 8];
#pragma unroll
        for (int mt = 0; mt < 2; ++mt) {
#pragma unroll
            for (int nd = 0; nd < 4; ++nd)
                o[mt][nd] = __builtin_amdgcn_mfma_f32_16x16x32_bf16(pf[mt], vf[nd], o[mt][nd], 0, 0, 0);
            lac[mt] = __builtin_amdgcn_mfma_f32_16x16x32_bf16(pf[mt], ones, lac[mt], 0, 0, 0);
        }
        __syncthreads();
    }

    // one-time 16-lane max reduction (raw logits; *0.125 afterwards is exact)
#pragma unroll
    for (int d = 1; d < 16; d <<= 1)
#pragma unroll
        for (int mt = 0; mt < 2; ++mt)
#pragma unroll
            for (int r = 0; r < 4; ++r)
                mxl[mt][r] = fmaxf(mxl[mt][r], __shfl_xor(mxl[mt][r], d, 64));

    // ---- fused combine epilogue (shift folded into hcf) ----
    const int b = mb / 12, h = mb - b * 12;
    const float rm = rowmax[mb * 128 + q];
    const float ln = low_norm[mb * 128 + q];
    const float* LO = low_out + ((size_t)mb * 128 + q) * 64;
#pragma unroll
    for (int mt = 0; mt < 2; ++mt)
#pragma unroll
        for (int r = 0; r < 4; ++r) {
            const int s = q * 32 + mt * 16 + quad * 4 + r;
            const float mv = fmaxf(mxl[mt][r] * 0.125f, -1e6f);
            const float hn = lac[mt][r];
            const float mk = mask[(b << 12) + s];
            const float lcr = (rm - mv) * mk;
            const float lcf = __expf(fminf(lcr, 0.f));
            const float hcf = __expf(-mv - fmaxf(lcr, 0.f));   // exp(-mv)*ref_hcf
            const float den = 1.0f / (hn * hcf + ln * lcf + 1e-6f);
            float* op = out + ((size_t)(b * 4096 + s)) * 768 + h * 64;
#pragma unroll
            for (int nd = 0; nd < 4; ++nd) {
                const int d = nd * 16 + l16;
                op[d] = (o[mt][nd][r] * hcf + LO[d] * lcf) * den;
            }
        }
}

extern "C" void kernel_launch(void* const* d_in, const int* in_sizes, int n_in,
                              void* d_out, int out_size, void* d_ws, size_t ws_size,
                              hipStream_t stream) {
    (void)in_sizes; (void)n_in; (void)out_size; (void)ws_size;
    const float* X    = (const float*)d_in[0];
    const float* mask = (const float*)d_in[1];
    const float* Wq   = (const float*)d_in[2];
    const float* bq   = (const float*)d_in[3];
    const float* Wk   = (const float*)d_in[4];
    const float* bk   = (const float*)d_in[5];
    const float* Wv   = (const float*)d_in[6];
    const float* bv   = (const float*)d_in[7];
    float* out = (float*)d_out;

    char* ws = (char*)d_ws;
    size_t off = 0;
    auto alloc = [&](size_t bytes) -> void* {
        off = (off + 255) & ~(size_t)255;
        void* p = ws + off;
        off += bytes;
        return p;
    };
    bf16* Xb  = (bf16*)alloc((size_t)8192 * 768 * 2);
    bf16* Wb  = (bf16*)alloc((size_t)2304 * 768 * 2);
    bf16* Qb  = (bf16*)alloc((size_t)24 * 4096 * 64 * 2);
    bf16* Kb  = (bf16*)alloc((size_t)24 * 4096 * 64 * 2);
    bf16* Vt  = (bf16*)alloc((size_t)24 * 4096 * 64 * 2);
    float* Xh = (float*)alloc((size_t)256 * 768 * 4);
    float* tc = (float*)alloc(256 * 4);
    float* Qh = (float*)alloc((size_t)24 * 128 * 64 * 4);
    float* Kh = (float*)alloc((size_t)24 * 128 * 64 * 4);
    float* Vh = (float*)alloc((size_t)24 * 128 * 64 * 4);
    float* prior = (float*)alloc((size_t)24 * 16384 * 4);
    float* rowmax = (float*)alloc(24 * 128 * 4);
    unsigned char* selmask = (unsigned char*)alloc((size_t)24 * 16384);
    unsigned short* lists = (unsigned short*)alloc((size_t)24 * 128 * 128 * 2);
    int* counts = (int*)alloc(24 * 128 * 4);
    ushort* qorder = (ushort*)alloc(24 * 128 * 2);
    float* low_out   = (float*)alloc((size_t)24 * 128 * 64 * 4);
    float* low_norm  = (float*)alloc(24 * 128 * 4);

    k_prep<<<256, 192, 0, stream>>>(X, mask, Xb, Xh, tc);
    k_convW<<<1728, 256, 0, stream>>>(Wq, Wk, Wv, Wb);
    k_gemm_qkv<<<dim3(64, 18), 256, 0, stream>>>(Xb, Wb, bq, bk, bv, mask, Qb, Kb, Vt);
    k_lowres<<<dim3(9, 32), 256, 0, stream>>>(Xh, tc, Wq, Wk, Wv, bq, bk, bv, Qh, Kh, Vh);
    k_lowlogit<<<dim3(24, 8), 256, 0, stream>>>(Qh, Kh, prior, rowmax);
    k_select<<<24, 1024, 0, stream>>>(prior, selmask, lists, counts, qorder);
    k_lowout<<<3072, 64, 0, stream>>>(prior, selmask, tc, Vh, low_out, low_norm);
    k_high<<<3072, 64, 0, stream>>>(Qb, Kb, Vt, counts, lists, qorder, rowmax, low_out,
                                    low_norm, mask, out);
}